// Round 4
// baseline (2558.313 us; speedup 1.0000x reference)
//
#include <hip/hip_runtime.h>
#include <math.h>

#define B_   2
#define N_   6
#define C_   64
#define D_   64
#define FH_  16
#define FW_  44
#define BN_  (B_*N_)              // 12
#define NPIX (BN_*FH_*FW_)        // 8448
#define BEVH 200
#define BEVW 200
#define NCELL (BEVH*BEVW)         // 40000

// ---------------- zero output ----------------
__global__ void zero_kernel(float4* __restrict__ p, int n4) {
    int i = blockIdx.x * blockDim.x + threadIdx.x;
    if (i < n4) p[i] = float4{0.f, 0.f, 0.f, 0.f};
}

// ---------------- prep: transpose weights, BN affine, Kinv ----------------
// Kinv emulates numpy/LAPACK f32 inverse (sgetf2 + strti2 + sgetri): numpy's
// linalg.inv on an f32 array stays f32, so the np reference's Kinv is f32.
__global__ __launch_bounds__(256) void prep_kernel(
        const float* __restrict__ w1, const float* __restrict__ w2,
        const float* __restrict__ gamma, const float* __restrict__ beta,
        const float* __restrict__ rmean, const float* __restrict__ rvar,
        const float* __restrict__ intr,
        float* __restrict__ w1t, float* __restrict__ w2t,
        float* __restrict__ bns, float* __restrict__ bnsh,
        float* __restrict__ kinv) {
#pragma clang fp contract(off)
    int t = threadIdx.x;
    // w1 (cout, cin, 3, 3) -> w1t[(cin*9+ky*3+kx)*64 + cout]
    for (int idx = t; idx < C_*C_*9; idx += 256) {
        int cout = idx / (C_*9);
        int r    = idx % (C_*9);
        w1t[r*C_ + cout] = w1[idx];
    }
    // w2 (d, c) -> w2t[c*64 + d]
    for (int idx = t; idx < D_*C_; idx += 256) {
        int d = idx / C_, c = idx % C_;
        w2t[c*D_ + d] = w2[idx];
    }
    if (t < C_) {
        float s = gamma[t] / sqrtf(rvar[t] + 1e-5f);
        bns[t]  = s;
        bnsh[t] = beta[t] - rmean[t] * s;
    }
    if (t < BN_) {
        const float* K = intr + t*9;
        float A[3][3];
        for (int r = 0; r < 3; r++)
            for (int cc = 0; cc < 3; cc++) A[r][cc] = K[r*3 + cc];
        int ipiv[3];
        // ---- sgetf2: LU with partial pivoting (reciprocal-scaled) ----
        for (int j = 0; j < 3; j++) {
            int p = j; float mx = fabsf(A[j][j]);
            for (int i = j+1; i < 3; i++) {
                float v = fabsf(A[i][j]);
                if (v > mx) { mx = v; p = i; }
            }
            ipiv[j] = p;
            if (p != j)
                for (int k = 0; k < 3; k++) { float tm = A[j][k]; A[j][k] = A[p][k]; A[p][k] = tm; }
            float rpiv = 1.0f / A[j][j];
            for (int i = j+1; i < 3; i++) A[i][j] = A[i][j] * rpiv;
            for (int k = j+1; k < 3; k++)
                for (int i = j+1; i < 3; i++)
                    A[i][k] = A[i][k] - A[i][j] * A[j][k];
        }
        // ---- strti2: invert U in place (upper, non-unit) ----
        for (int j = 0; j < 3; j++) {
            float ajj = 1.0f / A[j][j];
            A[j][j] = ajj;
            float najj = -ajj;
            for (int jj = 0; jj < j; jj++) {
                float temp = A[jj][j];
                for (int i = 0; i < jj; i++) A[i][j] = A[i][j] + temp * A[i][jj];
                A[jj][j] = A[jj][j] * A[jj][jj];
            }
            for (int i = 0; i < j; i++) A[i][j] = A[i][j] * najj;
        }
        // ---- sgetri: inv(A) = inv(U) * inv(L) ----
        for (int j = 1; j >= 0; j--) {
            float work[3];
            for (int i = j+1; i < 3; i++) { work[i] = A[i][j]; A[i][j] = 0.0f; }
            for (int k = j+1; k < 3; k++)
                for (int i = 0; i < 3; i++)
                    A[i][j] = A[i][j] - A[i][k] * work[k];
        }
        for (int j = 2; j >= 0; j--) {
            int p = ipiv[j];
            if (p != j)
                for (int i = 0; i < 3; i++) { float tm = A[i][j]; A[i][j] = A[i][p]; A[i][p] = tm; }
        }
        for (int k = 0; k < 9; k++) kinv[t*9 + k] = A[k/3][k%3];
    }
}

// ---------------- fused conv3x3+BN+ReLU+conv1x1+softmax ----------------
__global__ __launch_bounds__(256) void enc_kernel(
        const float* __restrict__ feat,
        const float* __restrict__ w1t, const float* __restrict__ w2t,
        const float* __restrict__ bns, const float* __restrict__ bnsh,
        const float* __restrict__ b1,  const float* __restrict__ b2,
        float* __restrict__ probs) {
    __shared__ float hl[FW_][C_];
    int row = blockIdx.x;
    int bn  = row / FH_;
    int y   = row % FH_;
    int t   = threadIdx.x;
    int c   = t & 63;
    int q   = __builtin_amdgcn_readfirstlane(t >> 6);

    float h[11];
    float b1v = b1[c];
#pragma unroll
    for (int j = 0; j < 11; j++) h[j] = b1v;

    const float* fbn = feat + (size_t)bn * C_ * FH_ * FW_;
    for (int ci = 0; ci < C_; ci++) {
        const float* fc   = fbn + ci * FH_ * FW_;
        const float* wrow = w1t + ci * 9 * C_;
#pragma unroll
        for (int ky = 0; ky < 3; ky++) {
            int iy2 = y + ky - 1;
            if (iy2 < 0 || iy2 >= FH_) continue;
            const float* frow = fc + iy2 * FW_;
#pragma unroll
            for (int kx = 0; kx < 3; kx++) {
                float wv = wrow[(ky*3 + kx)*C_ + c];
#pragma unroll
                for (int j = 0; j < 11; j++) {
                    int xs = q + 4*j + kx - 1;
                    if (xs >= 0 && xs < FW_)
                        h[j] = fmaf(wv, frow[xs], h[j]);
                }
            }
        }
    }
    float sc = bns[c], sh = bnsh[c];
#pragma unroll
    for (int j = 0; j < 11; j++) {
        float v = fmaf(h[j], sc, sh);
        hl[q + 4*j][c] = v > 0.f ? v : 0.f;
    }
    __syncthreads();

    float l[11];
    float b2v = b2[c];
#pragma unroll
    for (int j = 0; j < 11; j++) l[j] = b2v;
    for (int c2 = 0; c2 < C_; c2++) {
        float wv = w2t[c2*D_ + c];
#pragma unroll
        for (int j = 0; j < 11; j++)
            l[j] = fmaf(wv, hl[q + 4*j][c2], l[j]);
    }

#pragma unroll
    for (int j = 0; j < 11; j++) {
        float m = l[j];
        for (int off = 32; off; off >>= 1) m = fmaxf(m, __shfl_xor(m, off));
        float e = expf(l[j] - m);
        float s = e;
        for (int off = 32; off; off >>= 1) s += __shfl_xor(s, off);
        int x = q + 4*j;
        probs[(((size_t)bn*FH_ + y)*FW_ + x)*D_ + c] = e / s;
    }
}

// ---------------- geometry: cell index per (bn, d, y, x) ----------------
// Emulates a numpy translation that PRESERVES jax's f32 dtypes end-to-end:
//   frustum = linspace computed in f64, cast once to f32 (dtype=float32),
//   pts = x*d in f32; cam/ego einsums = per-op-rounded f32 mul/add, j
//   ascending, NO fma (numpy einsum); +t separate f32 add; (ego+50)/0.5
//   exact; floorf in f32.
__global__ __launch_bounds__(256) void geom_kernel(
        const float* __restrict__ ext, const float* __restrict__ kinv,
        int* __restrict__ cells) {
#pragma clang fp contract(off)
    int i = blockIdx.x * blockDim.x + threadIdx.x;
    if (i >= BN_ * D_ * FH_ * FW_) return;
    int x  = i % FW_;
    int y  = (i / FW_) % FH_;
    int d  = (i / (FW_*FH_)) % D_;
    int bn = i / (FW_*FH_*D_);

    const float* kv = kinv + bn*9;
    const float* e  = ext  + bn*16;

    // f64-computed linspace values, cast once to f32; endpoints exact
    float u  = (x == FW_-1) ? 703.0f : (float)((double)x * (703.0/43.0));
    float vv = (float)((double)y * 17.0);
    float dd = (d == D_-1) ? 60.0f  : (float)(1.0 + (double)d * (59.0/63.0));

    float px = u * dd;
    float py = vv * dd;
    float pz = dd;

    float cx = (kv[0]*px + kv[1]*py) + kv[2]*pz;
    float cy = (kv[3]*px + kv[4]*py) + kv[5]*pz;
    float cz = (kv[6]*px + kv[7]*py) + kv[8]*pz;

    float ex = (e[0]*cx + e[1]*cy) + e[2]*cz;
    float ey = (e[4]*cx + e[5]*cy) + e[6]*cz;
    ex = ex + e[3];
    ey = ey + e[7];

    float gx = (ex + 50.0f) / 0.5f;
    float gy = (ey + 50.0f) / 0.5f;
    int ix = (int)floorf(gx);
    int iy = (int)floorf(gy);
    int cell = (ix >= 0 && ix < BEVW && iy >= 0 && iy < BEVH) ? (iy*BEVW + ix) : -1;
    cells[i] = cell;
}

// ---------------- splat: one wave per ray (b,n,y,x), lane = channel ----------------
__global__ __launch_bounds__(256) void splat_kernel(
        const float* __restrict__ feat, const float* __restrict__ probs,
        const int* __restrict__ cells, float* __restrict__ out) {
    int gid  = blockIdx.x * blockDim.x + threadIdx.x;
    int wid  = gid >> 6;           // ray id, 0..8447
    int lane = gid & 63;
    if (wid >= NPIX) return;
    int x  = wid % FW_;
    int y  = (wid / FW_) % FH_;
    int bn = wid / (FW_*FH_);
    int b  = bn / N_;

    float f  = feat [(((size_t)bn*C_ + lane)*FH_ + y)*FW_ + x];
    float pv = probs[(((size_t)bn*FH_ + y)*FW_ + x)*D_ + lane];
    int   cv = cells[((size_t)bn*D_ + lane)*(FH_*FW_) + y*FW_ + x];

    float* outb = out + ((size_t)b*C_ + lane)*NCELL;

    for (int d = 0; d < D_; d++) {
        float w    = __shfl(pv, d);
        int   cell = __shfl(cv, d);
        if (cell >= 0) atomicAdd(&outb[cell], f * w);
    }
}

extern "C" void kernel_launch(void* const* d_in, const int* in_sizes, int n_in,
                              void* d_out, int out_size, void* d_ws, size_t ws_size,
                              hipStream_t stream) {
    const float* feat  = (const float*)d_in[0];
    const float* intr  = (const float*)d_in[1];
    const float* ext   = (const float*)d_in[2];
    const float* w1    = (const float*)d_in[3];
    const float* b1    = (const float*)d_in[4];
    const float* gamma = (const float*)d_in[5];
    const float* beta  = (const float*)d_in[6];
    const float* rmean = (const float*)d_in[7];
    const float* rvar  = (const float*)d_in[8];
    const float* w2    = (const float*)d_in[9];
    const float* b2    = (const float*)d_in[10];
    float* out = (float*)d_out;

    // workspace layout
    float*  w1t   = (float*)d_ws;                 // 36864 f32
    float*  w2t   = w1t + C_*C_*9;                // 4096
    float*  bns   = w2t + D_*C_;                  // 64
    float*  bnsh  = bns + C_;                     // 64
    float*  kinv  = bnsh + C_;                    // 108 f32
    float*  probs = kinv + BN_*9;                 // 540672 f32
    int*    cells = (int*)(probs + (size_t)BN_*FH_*FW_*D_); // 540672 i32
    (void)in_sizes; (void)n_in; (void)ws_size;

    // 1. zero output
    int n4 = out_size / 4;
    zero_kernel<<<(n4 + 255)/256, 256, 0, stream>>>((float4*)out, n4);

    // 2. prep
    prep_kernel<<<1, 256, 0, stream>>>(w1, w2, gamma, beta, rmean, rvar, intr,
                                       w1t, w2t, bns, bnsh, kinv);

    // 3. fused encoder -> depth probs
    enc_kernel<<<BN_*FH_, 256, 0, stream>>>(feat, w1t, w2t, bns, bnsh, b1, b2, probs);

    // 4. geometry -> cell indices
    int ngeom = BN_*D_*FH_*FW_;
    geom_kernel<<<ngeom/256, 256, 0, stream>>>(ext, kinv, cells);

    // 5. splat (atomic scatter-add)
    splat_kernel<<<(NPIX*64)/256, 256, 0, stream>>>(feat, probs, cells, out);
}

// Round 5
// 2427.502 us; speedup vs baseline: 1.0539x; 1.0539x over previous
//
#include <hip/hip_runtime.h>
#include <math.h>

#define B_   2
#define N_   6
#define C_   64
#define D_   64
#define FH_  16
#define FW_  44
#define BN_  (B_*N_)              // 12
#define PIX_ (FH_*FW_)            // 704
#define NPIX (BN_*PIX_)           // 8448
#define NPTS (BN_*D_*PIX_)        // 540672
#define PPBN (D_*PIX_)            // 45056 points per (b,n) image
#define BEVH 200
#define BEVW 200
#define NCELL (BEVH*BEVW)         // 40000
#define NBCELL (B_*NCELL)         // 80000

// ---------------- zero helpers ----------------
__global__ void zero_f4_kernel(float4* __restrict__ p, int n4) {
    int i = blockIdx.x * blockDim.x + threadIdx.x;
    if (i < n4) p[i] = float4{0.f, 0.f, 0.f, 0.f};
}
__global__ void zero_i_kernel(int* __restrict__ p, int n) {
    int i = blockIdx.x * blockDim.x + threadIdx.x;
    if (i < n) p[i] = 0;
}

// ---------------- prep: transpose weights, BN affine, Kinv ----------------
// Kinv emulates numpy/LAPACK f32 inverse (sgetf2 + strti2 + sgetri).
__global__ __launch_bounds__(256) void prep_kernel(
        const float* __restrict__ w1, const float* __restrict__ w2,
        const float* __restrict__ gamma, const float* __restrict__ beta,
        const float* __restrict__ rmean, const float* __restrict__ rvar,
        const float* __restrict__ intr,
        float* __restrict__ w1t, float* __restrict__ w2t,
        float* __restrict__ bns, float* __restrict__ bnsh,
        float* __restrict__ kinv) {
#pragma clang fp contract(off)
    int t = threadIdx.x;
    for (int idx = t; idx < C_*C_*9; idx += 256) {
        int cout = idx / (C_*9);
        int r    = idx % (C_*9);
        w1t[r*C_ + cout] = w1[idx];
    }
    for (int idx = t; idx < D_*C_; idx += 256) {
        int d = idx / C_, c = idx % C_;
        w2t[c*D_ + d] = w2[idx];
    }
    if (t < C_) {
        float s = gamma[t] / sqrtf(rvar[t] + 1e-5f);
        bns[t]  = s;
        bnsh[t] = beta[t] - rmean[t] * s;
    }
    if (t < BN_) {
        const float* K = intr + t*9;
        float A[3][3];
        for (int r = 0; r < 3; r++)
            for (int cc = 0; cc < 3; cc++) A[r][cc] = K[r*3 + cc];
        int ipiv[3];
        for (int j = 0; j < 3; j++) {
            int p = j; float mx = fabsf(A[j][j]);
            for (int i = j+1; i < 3; i++) {
                float v = fabsf(A[i][j]);
                if (v > mx) { mx = v; p = i; }
            }
            ipiv[j] = p;
            if (p != j)
                for (int k = 0; k < 3; k++) { float tm = A[j][k]; A[j][k] = A[p][k]; A[p][k] = tm; }
            float rpiv = 1.0f / A[j][j];
            for (int i = j+1; i < 3; i++) A[i][j] = A[i][j] * rpiv;
            for (int k = j+1; k < 3; k++)
                for (int i = j+1; i < 3; i++)
                    A[i][k] = A[i][k] - A[i][j] * A[j][k];
        }
        for (int j = 0; j < 3; j++) {
            float ajj = 1.0f / A[j][j];
            A[j][j] = ajj;
            float najj = -ajj;
            for (int jj = 0; jj < j; jj++) {
                float temp = A[jj][j];
                for (int i = 0; i < jj; i++) A[i][j] = A[i][j] + temp * A[i][jj];
                A[jj][j] = A[jj][j] * A[jj][jj];
            }
            for (int i = 0; i < j; i++) A[i][j] = A[i][j] * najj;
        }
        for (int j = 1; j >= 0; j--) {
            float work[3];
            for (int i = j+1; i < 3; i++) { work[i] = A[i][j]; A[i][j] = 0.0f; }
            for (int k = j+1; k < 3; k++)
                for (int i = 0; i < 3; i++)
                    A[i][j] = A[i][j] - A[i][k] * work[k];
        }
        for (int j = 2; j >= 0; j--) {
            int p = ipiv[j];
            if (p != j)
                for (int i = 0; i < 3; i++) { float tm = A[i][j]; A[i][j] = A[i][p]; A[i][p] = tm; }
        }
        for (int k = 0; k < 9; k++) kinv[t*9 + k] = A[k/3][k%3];
    }
}

// ---------------- feat transpose: [bn][c][pix] -> [bn*704+pix][c] ----------------
// 704 = 64*11, so 64-pixel tiles never straddle images. grid = 132 blocks.
__global__ __launch_bounds__(256) void featT_kernel(
        const float* __restrict__ feat, float* __restrict__ feat_t) {
    __shared__ float lds[64][65];
    int j    = blockIdx.x;
    int bn   = j / 11;
    int pb   = (j % 11) * 64;
    int t    = threadIdx.x;
    int lane = t & 63;
    int r0   = t >> 6;
#pragma unroll
    for (int rr = 0; rr < 16; rr++) {
        int c = r0 + 4*rr;
        lds[c][lane] = feat[((size_t)bn*C_ + c)*PIX_ + pb + lane];
    }
    __syncthreads();
#pragma unroll
    for (int rr = 0; rr < 16; rr++) {
        int pr = r0 + 4*rr;
        feat_t[((size_t)bn*PIX_ + pb + pr)*C_ + lane] = lds[lane][pr];
    }
}

// ---------------- fused conv3x3+BN+ReLU+conv1x1+softmax ----------------
__global__ __launch_bounds__(256) void enc_kernel(
        const float* __restrict__ feat,
        const float* __restrict__ w1t, const float* __restrict__ w2t,
        const float* __restrict__ bns, const float* __restrict__ bnsh,
        const float* __restrict__ b1,  const float* __restrict__ b2,
        float* __restrict__ probs) {
    __shared__ float hl[FW_][C_];
    int row = blockIdx.x;
    int bn  = row / FH_;
    int y   = row % FH_;
    int t   = threadIdx.x;
    int c   = t & 63;
    int q   = __builtin_amdgcn_readfirstlane(t >> 6);

    float h[11];
    float b1v = b1[c];
#pragma unroll
    for (int j = 0; j < 11; j++) h[j] = b1v;

    const float* fbn = feat + (size_t)bn * C_ * PIX_;
    for (int ci = 0; ci < C_; ci++) {
        const float* fc   = fbn + ci * PIX_;
        const float* wrow = w1t + ci * 9 * C_;
#pragma unroll
        for (int ky = 0; ky < 3; ky++) {
            int iy2 = y + ky - 1;
            if (iy2 < 0 || iy2 >= FH_) continue;
            const float* frow = fc + iy2 * FW_;
#pragma unroll
            for (int kx = 0; kx < 3; kx++) {
                float wv = wrow[(ky*3 + kx)*C_ + c];
#pragma unroll
                for (int j = 0; j < 11; j++) {
                    int xs = q + 4*j + kx - 1;
                    if (xs >= 0 && xs < FW_)
                        h[j] = fmaf(wv, frow[xs], h[j]);
                }
            }
        }
    }
    float sc = bns[c], sh = bnsh[c];
#pragma unroll
    for (int j = 0; j < 11; j++) {
        float v = fmaf(h[j], sc, sh);
        hl[q + 4*j][c] = v > 0.f ? v : 0.f;
    }
    __syncthreads();

    float l[11];
    float b2v = b2[c];
#pragma unroll
    for (int j = 0; j < 11; j++) l[j] = b2v;
    for (int c2 = 0; c2 < C_; c2++) {
        float wv = w2t[c2*D_ + c];
#pragma unroll
        for (int j = 0; j < 11; j++)
            l[j] = fmaf(wv, hl[q + 4*j][c2], l[j]);
    }

#pragma unroll
    for (int j = 0; j < 11; j++) {
        float m = l[j];
        for (int off = 32; off; off >>= 1) m = fmaxf(m, __shfl_xor(m, off));
        float e = expf(l[j] - m);
        float s = e;
        for (int off = 32; off; off >>= 1) s += __shfl_xor(s, off);
        int x = q + 4*j;
        probs[(((size_t)bn*FH_ + y)*FW_ + x)*D_ + c] = e / s;
    }
}

// ---------------- geometry: cell index per point ----------------
// f32 chain matching the numpy reference (validated round 4).
__global__ __launch_bounds__(256) void geom_kernel(
        const float* __restrict__ ext, const float* __restrict__ kinv,
        int* __restrict__ cells) {
#pragma clang fp contract(off)
    int i = blockIdx.x * blockDim.x + threadIdx.x;
    if (i >= NPTS) return;
    int x  = i % FW_;
    int y  = (i / FW_) % FH_;
    int d  = (i / PIX_) % D_;
    int bn = i / PPBN;

    const float* kv = kinv + bn*9;
    const float* e  = ext  + bn*16;

    float u  = (x == FW_-1) ? 703.0f : (float)((double)x * (703.0/43.0));
    float vv = (float)((double)y * 17.0);
    float dd = (d == D_-1) ? 60.0f  : (float)(1.0 + (double)d * (59.0/63.0));

    float px = u * dd;
    float py = vv * dd;
    float pz = dd;

    float cx = (kv[0]*px + kv[1]*py) + kv[2]*pz;
    float cy = (kv[3]*px + kv[4]*py) + kv[5]*pz;
    float cz = (kv[6]*px + kv[7]*py) + kv[8]*pz;

    float ex = (e[0]*cx + e[1]*cy) + e[2]*cz;
    float ey = (e[4]*cx + e[5]*cy) + e[6]*cz;
    ex = ex + e[3];
    ey = ey + e[7];

    float gx = (ex + 50.0f) / 0.5f;
    float gy = (ey + 50.0f) / 0.5f;
    int ix = (int)floorf(gx);
    int iy = (int)floorf(gy);
    int cell = (ix >= 0 && ix < BEVW && iy >= 0 && iy < BEVH) ? (iy*BEVW + ix) : -1;
    cells[i] = cell;
}

// ---------------- counting sort: histogram ----------------
__global__ __launch_bounds__(256) void hist_kernel(
        const int* __restrict__ cells, int* __restrict__ counts) {
    int i = blockIdx.x * blockDim.x + threadIdx.x;
    if (i >= NPTS) return;
    int cell = cells[i];
    if (cell < 0) return;
    int b = (i / PPBN) / N_;
    atomicAdd(&counts[b*NCELL + cell], 1);
}

// ---------------- exclusive scan over NBCELL counters (single block) -------
// in: startp[1+k] = count_k (k in [0,NBCELL)), startp[0] = 0
// out: startp[k]  = exclusive prefix (startp[NBCELL] = total), cursor[k] = startp[k]
__global__ __launch_bounds__(1024) void scan_kernel(
        int* __restrict__ startp, int* __restrict__ cursor) {
    __shared__ int sdata[1024];
    const int CH = (NBCELL + 1023) / 1024;   // 79
    int t  = threadIdx.x;
    int k0 = t * CH;
    int k1 = min(k0 + CH, NBCELL);
    int local = 0;
    for (int k = k0; k < k1; k++) local += startp[1 + k];
    sdata[t] = local;
    __syncthreads();
    for (int off = 1; off < 1024; off <<= 1) {
        int add = (t >= off) ? sdata[t - off] : 0;
        __syncthreads();
        sdata[t] += add;
        __syncthreads();
    }
    int running = (t == 0) ? 0 : sdata[t - 1];
    for (int k = k0; k < k1; k++) {
        int cnt = startp[1 + k];
        cursor[k] = running;
        running += cnt;
        startp[1 + k] = running;
    }
    // startp[0] stays 0: startp[k] is now the exclusive prefix of cell k.
}

// ---------------- scatter point ids into per-cell lists ----------------
__global__ __launch_bounds__(256) void scatter_kernel(
        const int* __restrict__ cells, int* __restrict__ cursor,
        int* __restrict__ plist) {
    int i = blockIdx.x * blockDim.x + threadIdx.x;
    if (i >= NPTS) return;
    int cell = cells[i];
    if (cell < 0) return;
    int b = (i / PPBN) / N_;
    int pos = atomicAdd(&cursor[b*NCELL + cell], 1);
    plist[pos] = i;
}

// ---------------- gather: block = 64 consecutive cells, lane = channel ----
// No atomics: register accumulation per cell, LDS transpose, coalesced store.
__global__ __launch_bounds__(256) void gather_kernel(
        const float* __restrict__ feat_t, const float* __restrict__ probs,
        const int* __restrict__ startp, const int* __restrict__ plist,
        float* __restrict__ out) {
    __shared__ float lds[64][65];
    int blk  = blockIdx.x;                 // 0..1249
    int b    = blk / (NCELL/64);           // NCELL/64 = 625
    int cb   = (blk % (NCELL/64)) * 64;    // cell base within batch
    int t    = threadIdx.x;
    int lane = t & 63;
    int wq   = t >> 6;

    for (int k = 0; k < 16; k++) {
        int kk   = wq*16 + k;              // 0..63 within block
        int fc   = b*NCELL + cb + kk;      // flat (b,cell)
        int s    = startp[fc];
        int epos = startp[fc + 1];
        float acc = 0.f;
        for (int p = s; p < epos; p++) {
            int id  = plist[p];
            int bn  = id / PPBN;
            int r   = id - bn*PPBN;
            int d   = r / PIX_;
            int pix = r - d*PIX_;
            float pr = probs[((size_t)bn*PIX_ + pix)*D_ + d];
            float fv = feat_t[((size_t)bn*PIX_ + pix)*C_ + lane];
            acc = fmaf(pr, fv, acc);
        }
        lds[kk][lane] = acc;
    }
    __syncthreads();
#pragma unroll
    for (int rr = 0; rr < 16; rr++) {
        int cidx = (t >> 6) + 4*rr;
        out[((size_t)b*C_ + cidx)*NCELL + cb + lane] = lds[lane][cidx];
    }
}

// ---------------- legacy splat (fallback if ws too small) ----------------
__global__ __launch_bounds__(256) void splat_kernel(
        const float* __restrict__ feat, const float* __restrict__ probs,
        const int* __restrict__ cells, float* __restrict__ out) {
    int gid  = blockIdx.x * blockDim.x + threadIdx.x;
    int wid  = gid >> 6;
    int lane = gid & 63;
    if (wid >= NPIX) return;
    int x  = wid % FW_;
    int y  = (wid / FW_) % FH_;
    int bn = wid / PIX_;
    int b  = bn / N_;

    float f  = feat [(((size_t)bn*C_ + lane)*FH_ + y)*FW_ + x];
    float pv = probs[(((size_t)bn*FH_ + y)*FW_ + x)*D_ + lane];
    int   cv = cells[((size_t)bn*D_ + lane)*PIX_ + y*FW_ + x];

    float* outb = out + ((size_t)b*C_ + lane)*NCELL;
    for (int d = 0; d < D_; d++) {
        float w    = __shfl(pv, d);
        int   cell = __shfl(cv, d);
        if (cell >= 0) atomicAdd(&outb[cell], f * w);
    }
}

extern "C" void kernel_launch(void* const* d_in, const int* in_sizes, int n_in,
                              void* d_out, int out_size, void* d_ws, size_t ws_size,
                              hipStream_t stream) {
    const float* feat  = (const float*)d_in[0];
    const float* intr  = (const float*)d_in[1];
    const float* ext   = (const float*)d_in[2];
    const float* w1    = (const float*)d_in[3];
    const float* b1    = (const float*)d_in[4];
    const float* gamma = (const float*)d_in[5];
    const float* beta  = (const float*)d_in[6];
    const float* rmean = (const float*)d_in[7];
    const float* rvar  = (const float*)d_in[8];
    const float* w2    = (const float*)d_in[9];
    const float* b2    = (const float*)d_in[10];
    float* out = (float*)d_out;
    (void)in_sizes; (void)n_in;

    // workspace layout (all 4-byte elems)
    float* w1t    = (float*)d_ws;                   // 36864
    float* w2t    = w1t + C_*C_*9;                  // 4096
    float* bns    = w2t + D_*C_;                    // 64
    float* bnsh   = bns + C_;                       // 64
    float* kinv   = bnsh + C_;                      // 108
    float* probs  = kinv + BN_*9;                   // 540672
    int*   cells  = (int*)(probs + NPTS);           // 540672
    float* feat_t = (float*)(cells + NPTS);         // 540672
    int*   startp = (int*)(feat_t + NPTS);          // 80001
    int*   cursor = startp + (NBCELL + 1);          // 80000
    int*   plist  = cursor + NBCELL;                // 540672
    size_t need   = (size_t)((plist + NPTS) - (int*)d_ws) * 4;

    if (ws_size >= need) {
        // ---- sorted-gather path ----
        int nz = NBCELL + 1 + NBCELL;   // startp + cursor
        zero_i_kernel<<<(nz + 255)/256, 256, 0, stream>>>(startp, nz);
        prep_kernel<<<1, 256, 0, stream>>>(w1, w2, gamma, beta, rmean, rvar, intr,
                                           w1t, w2t, bns, bnsh, kinv);
        featT_kernel<<<NPIX/64, 256, 0, stream>>>(feat, feat_t);
        enc_kernel<<<BN_*FH_, 256, 0, stream>>>(feat, w1t, w2t, bns, bnsh, b1, b2, probs);
        geom_kernel<<<NPTS/256, 256, 0, stream>>>(ext, kinv, cells);
        hist_kernel<<<NPTS/256, 256, 0, stream>>>(cells, startp + 1);
        scan_kernel<<<1, 1024, 0, stream>>>(startp, cursor);
        scatter_kernel<<<NPTS/256, 256, 0, stream>>>(cells, cursor, plist);
        gather_kernel<<<NBCELL/64, 256, 0, stream>>>(feat_t, probs, startp, plist, out);
    } else {
        // ---- legacy atomic-splat path ----
        int n4 = out_size / 4;
        zero_f4_kernel<<<(n4 + 255)/256, 256, 0, stream>>>((float4*)out, n4);
        prep_kernel<<<1, 256, 0, stream>>>(w1, w2, gamma, beta, rmean, rvar, intr,
                                           w1t, w2t, bns, bnsh, kinv);
        enc_kernel<<<BN_*FH_, 256, 0, stream>>>(feat, w1t, w2t, bns, bnsh, b1, b2, probs);
        geom_kernel<<<NPTS/256, 256, 0, stream>>>(ext, kinv, cells);
        splat_kernel<<<(NPIX*64)/256, 256, 0, stream>>>(feat, probs, cells, out);
    }
}

// Round 6
// 907.993 us; speedup vs baseline: 2.8175x; 2.6735x over previous
//
#include <hip/hip_runtime.h>
#include <math.h>

#define B_   2
#define N_   6
#define C_   64
#define D_   64
#define FH_  16
#define FW_  44
#define BN_  (B_*N_)              // 12
#define PIX_ (FH_*FW_)            // 704
#define NPIX (BN_*PIX_)           // 8448
#define NPTS (BN_*D_*PIX_)        // 540672
#define PPBN (D_*PIX_)            // 45056 points per (b,n) image
#define BEVH 200
#define BEVW 200
#define NCELL (BEVH*BEVW)         // 40000
#define NBCELL (B_*NCELL)         // 80000
#define NTILE (NBCELL/64)         // 1250 tiles of 64 consecutive cells

// ---------------- zero helpers ----------------
__global__ void zero_f4_kernel(float4* __restrict__ p, int n4) {
    int i = blockIdx.x * blockDim.x + threadIdx.x;
    if (i < n4) p[i] = float4{0.f, 0.f, 0.f, 0.f};
}
__global__ void zero_i_kernel(int* __restrict__ p, int n) {
    int i = blockIdx.x * blockDim.x + threadIdx.x;
    if (i < n) p[i] = 0;
}

// ---------------- prep: transpose weights, BN affine, Kinv ----------------
// Kinv emulates numpy/LAPACK f32 inverse (sgetf2 + strti2 + sgetri).
__global__ __launch_bounds__(256) void prep_kernel(
        const float* __restrict__ w1, const float* __restrict__ w2,
        const float* __restrict__ gamma, const float* __restrict__ beta,
        const float* __restrict__ rmean, const float* __restrict__ rvar,
        const float* __restrict__ intr,
        float* __restrict__ w1t, float* __restrict__ w2t,
        float* __restrict__ bns, float* __restrict__ bnsh,
        float* __restrict__ kinv) {
#pragma clang fp contract(off)
    int t = threadIdx.x;
    for (int idx = t; idx < C_*C_*9; idx += 256) {
        int cout = idx / (C_*9);
        int r    = idx % (C_*9);
        w1t[r*C_ + cout] = w1[idx];
    }
    for (int idx = t; idx < D_*C_; idx += 256) {
        int d = idx / C_, c = idx % C_;
        w2t[c*D_ + d] = w2[idx];
    }
    if (t < C_) {
        float s = gamma[t] / sqrtf(rvar[t] + 1e-5f);
        bns[t]  = s;
        bnsh[t] = beta[t] - rmean[t] * s;
    }
    if (t < BN_) {
        const float* K = intr + t*9;
        float A[3][3];
        for (int r = 0; r < 3; r++)
            for (int cc = 0; cc < 3; cc++) A[r][cc] = K[r*3 + cc];
        int ipiv[3];
        for (int j = 0; j < 3; j++) {
            int p = j; float mx = fabsf(A[j][j]);
            for (int i = j+1; i < 3; i++) {
                float v = fabsf(A[i][j]);
                if (v > mx) { mx = v; p = i; }
            }
            ipiv[j] = p;
            if (p != j)
                for (int k = 0; k < 3; k++) { float tm = A[j][k]; A[j][k] = A[p][k]; A[p][k] = tm; }
            float rpiv = 1.0f / A[j][j];
            for (int i = j+1; i < 3; i++) A[i][j] = A[i][j] * rpiv;
            for (int k = j+1; k < 3; k++)
                for (int i = j+1; i < 3; i++)
                    A[i][k] = A[i][k] - A[i][j] * A[j][k];
        }
        for (int j = 0; j < 3; j++) {
            float ajj = 1.0f / A[j][j];
            A[j][j] = ajj;
            float najj = -ajj;
            for (int jj = 0; jj < j; jj++) {
                float temp = A[jj][j];
                for (int i = 0; i < jj; i++) A[i][j] = A[i][j] + temp * A[i][jj];
                A[jj][j] = A[jj][j] * A[jj][jj];
            }
            for (int i = 0; i < j; i++) A[i][j] = A[i][j] * najj;
        }
        for (int j = 1; j >= 0; j--) {
            float work[3];
            for (int i = j+1; i < 3; i++) { work[i] = A[i][j]; A[i][j] = 0.0f; }
            for (int k = j+1; k < 3; k++)
                for (int i = 0; i < 3; i++)
                    A[i][j] = A[i][j] - A[i][k] * work[k];
        }
        for (int j = 2; j >= 0; j--) {
            int p = ipiv[j];
            if (p != j)
                for (int i = 0; i < 3; i++) { float tm = A[i][j]; A[i][j] = A[i][p]; A[i][p] = tm; }
        }
        for (int k = 0; k < 9; k++) kinv[t*9 + k] = A[k/3][k%3];
    }
}

// ---------------- feat transpose: [bn][c][pix] -> [bn*704+pix][c] ----------------
__global__ __launch_bounds__(256) void featT_kernel(
        const float* __restrict__ feat, float* __restrict__ feat_t) {
    __shared__ float lds[64][65];
    int j    = blockIdx.x;
    int bn   = j / 11;
    int pb   = (j % 11) * 64;
    int t    = threadIdx.x;
    int lane = t & 63;
    int r0   = t >> 6;
#pragma unroll
    for (int rr = 0; rr < 16; rr++) {
        int c = r0 + 4*rr;
        lds[c][lane] = feat[((size_t)bn*C_ + c)*PIX_ + pb + lane];
    }
    __syncthreads();
#pragma unroll
    for (int rr = 0; rr < 16; rr++) {
        int pr = r0 + 4*rr;
        feat_t[((size_t)bn*PIX_ + pb + pr)*C_ + lane] = lds[lane][pr];
    }
}

// ---------------- fused conv3x3+BN+ReLU+conv1x1+softmax ----------------
__global__ __launch_bounds__(256) void enc_kernel(
        const float* __restrict__ feat,
        const float* __restrict__ w1t, const float* __restrict__ w2t,
        const float* __restrict__ bns, const float* __restrict__ bnsh,
        const float* __restrict__ b1,  const float* __restrict__ b2,
        float* __restrict__ probs) {
    __shared__ float hl[FW_][C_];
    int row = blockIdx.x;
    int bn  = row / FH_;
    int y   = row % FH_;
    int t   = threadIdx.x;
    int c   = t & 63;
    int q   = __builtin_amdgcn_readfirstlane(t >> 6);

    float h[11];
    float b1v = b1[c];
#pragma unroll
    for (int j = 0; j < 11; j++) h[j] = b1v;

    const float* fbn = feat + (size_t)bn * C_ * PIX_;
    for (int ci = 0; ci < C_; ci++) {
        const float* fc   = fbn + ci * PIX_;
        const float* wrow = w1t + ci * 9 * C_;
#pragma unroll
        for (int ky = 0; ky < 3; ky++) {
            int iy2 = y + ky - 1;
            if (iy2 < 0 || iy2 >= FH_) continue;
            const float* frow = fc + iy2 * FW_;
#pragma unroll
            for (int kx = 0; kx < 3; kx++) {
                float wv = wrow[(ky*3 + kx)*C_ + c];
#pragma unroll
                for (int j = 0; j < 11; j++) {
                    int xs = q + 4*j + kx - 1;
                    if (xs >= 0 && xs < FW_)
                        h[j] = fmaf(wv, frow[xs], h[j]);
                }
            }
        }
    }
    float sc = bns[c], sh = bnsh[c];
#pragma unroll
    for (int j = 0; j < 11; j++) {
        float v = fmaf(h[j], sc, sh);
        hl[q + 4*j][c] = v > 0.f ? v : 0.f;
    }
    __syncthreads();

    float l[11];
    float b2v = b2[c];
#pragma unroll
    for (int j = 0; j < 11; j++) l[j] = b2v;
    for (int c2 = 0; c2 < C_; c2++) {
        float wv = w2t[c2*D_ + c];
#pragma unroll
        for (int j = 0; j < 11; j++)
            l[j] = fmaf(wv, hl[q + 4*j][c2], l[j]);
    }

#pragma unroll
    for (int j = 0; j < 11; j++) {
        float m = l[j];
        for (int off = 32; off; off >>= 1) m = fmaxf(m, __shfl_xor(m, off));
        float e = expf(l[j] - m);
        float s = e;
        for (int off = 32; off; off >>= 1) s += __shfl_xor(s, off);
        int x = q + 4*j;
        probs[(((size_t)bn*FH_ + y)*FW_ + x)*D_ + c] = e / s;
    }
}

// ---------------- geometry: cell for point i (f32 chain, validated r4) ------
__device__ __forceinline__ int compute_cell(int i, const float* __restrict__ kinv,
                                            const float* __restrict__ ext) {
#pragma clang fp contract(off)
    int x  = i % FW_;
    int y  = (i / FW_) % FH_;
    int d  = (i / PIX_) % D_;
    int bn = i / PPBN;

    const float* kv = kinv + bn*9;
    const float* e  = ext  + bn*16;

    float u  = (x == FW_-1) ? 703.0f : (float)((double)x * (703.0/43.0));
    float vv = (float)((double)y * 17.0);
    float dd = (d == D_-1) ? 60.0f  : (float)(1.0 + (double)d * (59.0/63.0));

    float px = u * dd;
    float py = vv * dd;
    float pz = dd;

    float cx = (kv[0]*px + kv[1]*py) + kv[2]*pz;
    float cy = (kv[3]*px + kv[4]*py) + kv[5]*pz;
    float cz = (kv[6]*px + kv[7]*py) + kv[8]*pz;

    float ex = (e[0]*cx + e[1]*cy) + e[2]*cz;
    float ey = (e[4]*cx + e[5]*cy) + e[6]*cz;
    ex = ex + e[3];
    ey = ey + e[7];

    float gx = (ex + 50.0f) / 0.5f;
    float gy = (ey + 50.0f) / 0.5f;
    int ix = (int)floorf(gx);
    int iy = (int)floorf(gy);
    return (ix >= 0 && ix < BEVW && iy >= 0 && iy < BEVH) ? (iy*BEVW + ix) : -1;
}

// ---------------- geom + histogram ----------------
__global__ __launch_bounds__(256) void geomhist_kernel(
        const float* __restrict__ ext, const float* __restrict__ kinv,
        int* __restrict__ counts) {
    int i = blockIdx.x * blockDim.x + threadIdx.x;
    if (i >= NPTS) return;
    int cell = compute_cell(i, kinv, ext);
    if (cell < 0) return;
    int b = i / (PPBN * N_);
    atomicAdd(&counts[b*NCELL + cell], 1);
}

// ---------------- exclusive scan over NBCELL counters (single block) -------
__global__ __launch_bounds__(1024) void scan_kernel(
        int* __restrict__ startp, int* __restrict__ cursor) {
    __shared__ int sdata[1024];
    const int CH = (NBCELL + 1023) / 1024;   // 79
    int t  = threadIdx.x;
    int k0 = t * CH;
    int k1 = min(k0 + CH, NBCELL);
    int local = 0;
    for (int k = k0; k < k1; k++) local += startp[1 + k];
    sdata[t] = local;
    __syncthreads();
    for (int off = 1; off < 1024; off <<= 1) {
        int add = (t >= off) ? sdata[t - off] : 0;
        __syncthreads();
        sdata[t] += add;
        __syncthreads();
    }
    int running = (t == 0) ? 0 : sdata[t - 1];
    for (int k = k0; k < k1; k++) {
        int cnt = startp[1 + k];
        cursor[k] = running;
        running += cnt;
        startp[1 + k] = running;
    }
}

// ---------------- geom + scatter packed records ----------------
// record: .x = prob bits, .y = pixg | (cell_local << 16)
__global__ __launch_bounds__(256) void geomscatter_kernel(
        const float* __restrict__ ext, const float* __restrict__ kinv,
        const float* __restrict__ probs,
        int* __restrict__ cursor, int2* __restrict__ plist2) {
    int i = blockIdx.x * blockDim.x + threadIdx.x;
    if (i >= NPTS) return;
    int cell = compute_cell(i, kinv, ext);
    if (cell < 0) return;
    int pix = i % PIX_;
    int d   = (i / PIX_) % D_;
    int bn  = i / PPBN;
    int b   = bn / N_;
    int pixg = bn*PIX_ + pix;
    float pr = probs[(size_t)pixg*D_ + d];
    int pos = atomicAdd(&cursor[b*NCELL + cell], 1);
    plist2[pos] = make_int2(__float_as_int(pr), pixg | ((cell & 63) << 16));
}

// ---------------- gather v2: tile = 64 consecutive cells, 16 waves ---------
// Waves split the tile's contiguous point range evenly BY POINTS; partial
// sums flush to LDS acc[cell][chan] via ds-atomics at cell boundaries only.
__global__ __launch_bounds__(1024) void gather2_kernel(
        const float* __restrict__ feat_t,
        const int* __restrict__ startp, const int2* __restrict__ plist2,
        float* __restrict__ out) {
    __shared__ float acc_s[64][65];
    int blk  = blockIdx.x;                 // 0..NTILE-1
    int b    = blk / (NCELL/64);           // 625 tiles per batch
    int cb   = (blk % (NCELL/64)) * 64;
    int t    = threadIdx.x;
    int lane = t & 63;
    int w    = __builtin_amdgcn_readfirstlane(t >> 6);   // wave id 0..15

    for (int idx = t; idx < 64*65; idx += 1024)
        ((float*)acc_s)[idx] = 0.f;
    __syncthreads();

    int fc0 = b*NCELL + cb;
    int s0  = startp[fc0];
    int e0  = startp[fc0 + 64];
    int n   = e0 - s0;
    int per = (n + 15) >> 4;
    int ps  = s0 + w * per;
    int pe  = min(ps + per, e0);

    float acc = 0.f;
    int   cur = -1;
    for (int p = ps; p < pe; p++) {
        int2 r = plist2[p];
        int cl = r.y >> 16;
        if (cl != cur) {
            if (cur >= 0) atomicAdd(&acc_s[cur][lane], acc);
            acc = 0.f; cur = cl;
        }
        acc = fmaf(__int_as_float(r.x),
                   feat_t[(size_t)(r.y & 0xFFFF)*C_ + lane], acc);
    }
    if (cur >= 0) atomicAdd(&acc_s[cur][lane], acc);
    __syncthreads();

    // transpose store: lane -> cell (coalesced 256B), w*4+rr -> channel
#pragma unroll
    for (int rr = 0; rr < 4; rr++) {
        int cidx = (w << 2) + rr;
        out[((size_t)b*C_ + cidx)*NCELL + cb + lane] = acc_s[lane][cidx];
    }
}

// ---------------- legacy fallback: geom->cells + atomic splat ----------------
__global__ __launch_bounds__(256) void geom_kernel(
        const float* __restrict__ ext, const float* __restrict__ kinv,
        int* __restrict__ cells) {
    int i = blockIdx.x * blockDim.x + threadIdx.x;
    if (i >= NPTS) return;
    cells[i] = compute_cell(i, kinv, ext);
}

__global__ __launch_bounds__(256) void splat_kernel(
        const float* __restrict__ feat, const float* __restrict__ probs,
        const int* __restrict__ cells, float* __restrict__ out) {
    int gid  = blockIdx.x * blockDim.x + threadIdx.x;
    int wid  = gid >> 6;
    int lane = gid & 63;
    if (wid >= NPIX) return;
    int x  = wid % FW_;
    int y  = (wid / FW_) % FH_;
    int bn = wid / PIX_;
    int b  = bn / N_;

    float f  = feat [(((size_t)bn*C_ + lane)*FH_ + y)*FW_ + x];
    float pv = probs[(((size_t)bn*FH_ + y)*FW_ + x)*D_ + lane];
    int   cv = cells[((size_t)bn*D_ + lane)*PIX_ + y*FW_ + x];

    float* outb = out + ((size_t)b*C_ + lane)*NCELL;
    for (int d = 0; d < D_; d++) {
        float wgt  = __shfl(pv, d);
        int   cell = __shfl(cv, d);
        if (cell >= 0) atomicAdd(&outb[cell], f * wgt);
    }
}

extern "C" void kernel_launch(void* const* d_in, const int* in_sizes, int n_in,
                              void* d_out, int out_size, void* d_ws, size_t ws_size,
                              hipStream_t stream) {
    const float* feat  = (const float*)d_in[0];
    const float* intr  = (const float*)d_in[1];
    const float* ext   = (const float*)d_in[2];
    const float* w1    = (const float*)d_in[3];
    const float* b1    = (const float*)d_in[4];
    const float* gamma = (const float*)d_in[5];
    const float* beta  = (const float*)d_in[6];
    const float* rmean = (const float*)d_in[7];
    const float* rvar  = (const float*)d_in[8];
    const float* w2    = (const float*)d_in[9];
    const float* b2    = (const float*)d_in[10];
    float* out = (float*)d_out;
    (void)in_sizes; (void)n_in;

    // workspace layout (plist2 first for 8B alignment)
    int2*  plist2 = (int2*)d_ws;                    // NPTS int2 = 4.33 MB
    float* w1t    = (float*)(plist2 + NPTS);        // 36864
    float* w2t    = w1t + C_*C_*9;                  // 4096
    float* bns    = w2t + D_*C_;                    // 64
    float* bnsh   = bns + C_;                       // 64
    float* kinv   = bnsh + C_;                      // 108
    float* probs  = kinv + BN_*9;                   // 540672
    float* feat_t = probs + NPTS;                   // 540672
    int*   startp = (int*)(feat_t + NPTS);          // 80001
    int*   cursor = startp + (NBCELL + 1);          // 80000
    size_t need   = (size_t)((cursor + NBCELL) - (int*)d_ws) * 4;

    if (ws_size >= need) {
        // ---- sorted-gather path (no output atomics, balanced gather) ----
        int nz = NBCELL + 1 + NBCELL;   // startp + cursor (contiguous)
        zero_i_kernel<<<(nz + 255)/256, 256, 0, stream>>>(startp, nz);
        prep_kernel<<<1, 256, 0, stream>>>(w1, w2, gamma, beta, rmean, rvar, intr,
                                           w1t, w2t, bns, bnsh, kinv);
        featT_kernel<<<NPIX/64, 256, 0, stream>>>(feat, feat_t);
        enc_kernel<<<BN_*FH_, 256, 0, stream>>>(feat, w1t, w2t, bns, bnsh, b1, b2, probs);
        geomhist_kernel<<<NPTS/256, 256, 0, stream>>>(ext, kinv, startp + 1);
        scan_kernel<<<1, 1024, 0, stream>>>(startp, cursor);
        geomscatter_kernel<<<NPTS/256, 256, 0, stream>>>(ext, kinv, probs, cursor, plist2);
        gather2_kernel<<<NTILE, 1024, 0, stream>>>(feat_t, startp, plist2, out);
    } else {
        // ---- legacy atomic-splat path ----
        float* f_w1t   = (float*)d_ws;
        float* f_w2t   = f_w1t + C_*C_*9;
        float* f_bns   = f_w2t + D_*C_;
        float* f_bnsh  = f_bns + C_;
        float* f_kinv  = f_bnsh + C_;
        float* f_probs = f_kinv + BN_*9;
        int*   f_cells = (int*)(f_probs + NPTS);
        int n4 = out_size / 4;
        zero_f4_kernel<<<(n4 + 255)/256, 256, 0, stream>>>((float4*)out, n4);
        prep_kernel<<<1, 256, 0, stream>>>(w1, w2, gamma, beta, rmean, rvar, intr,
                                           f_w1t, f_w2t, f_bns, f_bnsh, f_kinv);
        enc_kernel<<<BN_*FH_, 256, 0, stream>>>(feat, f_w1t, f_w2t, f_bns, f_bnsh, b1, b2, f_probs);
        geom_kernel<<<NPTS/256, 256, 0, stream>>>(ext, f_kinv, f_cells);
        splat_kernel<<<(NPIX*64)/256, 256, 0, stream>>>(feat, f_probs, f_cells, out);
    }
}

// Round 7
// 734.886 us; speedup vs baseline: 3.4812x; 1.2356x over previous
//
#include <hip/hip_runtime.h>
#include <math.h>

#define B_   2
#define N_   6
#define C_   64
#define D_   64
#define FH_  16
#define FW_  44
#define BN_  (B_*N_)              // 12
#define PIX_ (FH_*FW_)            // 704
#define NPIX (BN_*PIX_)           // 8448
#define NPTS (BN_*D_*PIX_)        // 540672
#define PPBN (D_*PIX_)            // 45056 points per (b,n) image
#define BEVH 200
#define BEVW 200
#define NCELL (BEVH*BEVW)         // 40000
#define NBCELL (B_*NCELL)         // 80000
#define NTILE (NBCELL/64)         // 1250 tiles of 64 consecutive cells

// ---------------- zero helpers ----------------
__global__ void zero_f4_kernel(float4* __restrict__ p, int n4) {
    int i = blockIdx.x * blockDim.x + threadIdx.x;
    if (i < n4) p[i] = float4{0.f, 0.f, 0.f, 0.f};
}
__global__ void zero_i_kernel(int* __restrict__ p, int n) {
    int i = blockIdx.x * blockDim.x + threadIdx.x;
    if (i < n) p[i] = 0;
}

// ---------------- prep: transpose weights, BN affine, Kinv ----------------
// Kinv emulates numpy/LAPACK f32 inverse (sgetf2 + strti2 + sgetri).
__global__ __launch_bounds__(256) void prep_kernel(
        const float* __restrict__ w1, const float* __restrict__ w2,
        const float* __restrict__ gamma, const float* __restrict__ beta,
        const float* __restrict__ rmean, const float* __restrict__ rvar,
        const float* __restrict__ intr,
        float* __restrict__ w1t, float* __restrict__ w2t,
        float* __restrict__ bns, float* __restrict__ bnsh,
        float* __restrict__ kinv) {
#pragma clang fp contract(off)
    int t = threadIdx.x;
    for (int idx = t; idx < C_*C_*9; idx += 256) {
        int cout = idx / (C_*9);
        int r    = idx % (C_*9);
        w1t[r*C_ + cout] = w1[idx];
    }
    for (int idx = t; idx < D_*C_; idx += 256) {
        int d = idx / C_, c = idx % C_;
        w2t[c*D_ + d] = w2[idx];
    }
    if (t < C_) {
        float s = gamma[t] / sqrtf(rvar[t] + 1e-5f);
        bns[t]  = s;
        bnsh[t] = beta[t] - rmean[t] * s;
    }
    if (t < BN_) {
        const float* K = intr + t*9;
        float A[3][3];
        for (int r = 0; r < 3; r++)
            for (int cc = 0; cc < 3; cc++) A[r][cc] = K[r*3 + cc];
        int ipiv[3];
        for (int j = 0; j < 3; j++) {
            int p = j; float mx = fabsf(A[j][j]);
            for (int i = j+1; i < 3; i++) {
                float v = fabsf(A[i][j]);
                if (v > mx) { mx = v; p = i; }
            }
            ipiv[j] = p;
            if (p != j)
                for (int k = 0; k < 3; k++) { float tm = A[j][k]; A[j][k] = A[p][k]; A[p][k] = tm; }
            float rpiv = 1.0f / A[j][j];
            for (int i = j+1; i < 3; i++) A[i][j] = A[i][j] * rpiv;
            for (int k = j+1; k < 3; k++)
                for (int i = j+1; i < 3; i++)
                    A[i][k] = A[i][k] - A[i][j] * A[j][k];
        }
        for (int j = 0; j < 3; j++) {
            float ajj = 1.0f / A[j][j];
            A[j][j] = ajj;
            float najj = -ajj;
            for (int jj = 0; jj < j; jj++) {
                float temp = A[jj][j];
                for (int i = 0; i < jj; i++) A[i][j] = A[i][j] + temp * A[i][jj];
                A[jj][j] = A[jj][j] * A[jj][jj];
            }
            for (int i = 0; i < j; i++) A[i][j] = A[i][j] * najj;
        }
        for (int j = 1; j >= 0; j--) {
            float work[3];
            for (int i = j+1; i < 3; i++) { work[i] = A[i][j]; A[i][j] = 0.0f; }
            for (int k = j+1; k < 3; k++)
                for (int i = 0; i < 3; i++)
                    A[i][j] = A[i][j] - A[i][k] * work[k];
        }
        for (int j = 2; j >= 0; j--) {
            int p = ipiv[j];
            if (p != j)
                for (int i = 0; i < 3; i++) { float tm = A[i][j]; A[i][j] = A[i][p]; A[i][p] = tm; }
        }
        for (int k = 0; k < 9; k++) kinv[t*9 + k] = A[k/3][k%3];
    }
}

// ---------------- feat transpose: [bn][c][pix] -> [bn*704+pix][c] ----------------
__global__ __launch_bounds__(256) void featT_kernel(
        const float* __restrict__ feat, float* __restrict__ feat_t) {
    __shared__ float lds[64][65];
    int j    = blockIdx.x;
    int bn   = j / 11;
    int pb   = (j % 11) * 64;
    int t    = threadIdx.x;
    int lane = t & 63;
    int r0   = t >> 6;
#pragma unroll
    for (int rr = 0; rr < 16; rr++) {
        int c = r0 + 4*rr;
        lds[c][lane] = feat[((size_t)bn*C_ + c)*PIX_ + pb + lane];
    }
    __syncthreads();
#pragma unroll
    for (int rr = 0; rr < 16; rr++) {
        int pr = r0 + 4*rr;
        feat_t[((size_t)bn*PIX_ + pb + pr)*C_ + lane] = lds[lane][pr];
    }
}

// ---------------- fused conv3x3+BN+ReLU+conv1x1+softmax, 1 wave = 1 pixel --
// grid = BN_*FH_*11 = 2112 blocks, 256 threads = 4 waves = 4 pixels.
// lane = cout (conv1) then depth bin (conv2); conv2 is 1x1 so no halo in LDS.
__global__ __launch_bounds__(256) void enc_kernel(
        const float* __restrict__ feat,
        const float* __restrict__ w1t, const float* __restrict__ w2t,
        const float* __restrict__ bns, const float* __restrict__ bnsh,
        const float* __restrict__ b1,  const float* __restrict__ b2,
        float* __restrict__ probs) {
    __shared__ float hl[4][C_];
    int blk = blockIdx.x;               // 0..2111
    int bn  = blk / (FH_*11);
    int rem = blk % (FH_*11);
    int y   = rem / 11;
    int t   = threadIdx.x;
    int c   = t & 63;
    int w   = __builtin_amdgcn_readfirstlane(t >> 6);   // wave id 0..3
    int x   = (rem % 11) * 4 + w;       // pixel for this wave (<44 always)

    // ---- conv1: lane = cout ----
    float h = b1[c];
    const float* fbn = feat + (size_t)bn * C_ * PIX_;
    for (int ci = 0; ci < C_; ci++) {
        const float* fc   = fbn + ci * PIX_;
        const float* wrow = w1t + ci * 9 * C_;
#pragma unroll
        for (int ky = 0; ky < 3; ky++) {
            int iy2 = y + ky - 1;
            if (iy2 < 0 || iy2 >= FH_) continue;       // block-uniform
            const float* frow = fc + iy2 * FW_;
#pragma unroll
            for (int kx = 0; kx < 3; kx++) {
                int xs = x + kx - 1;
                if (xs < 0 || xs >= FW_) continue;     // wave-uniform
                h = fmaf(wrow[(ky*3 + kx)*C_ + c], frow[xs], h);
            }
        }
    }
    // ---- BN + ReLU -> LDS ----
    float v = fmaf(h, bns[c], bnsh[c]);
    hl[w][c] = v > 0.f ? v : 0.f;
    __syncthreads();

    // ---- conv2 (1x1): lane = depth bin ----
    float l = b2[c];
    for (int c2 = 0; c2 < C_; c2++)
        l = fmaf(w2t[c2*D_ + c], hl[w][c2], l);

    // ---- softmax over the 64 lanes ----
    float m = l;
    for (int off = 32; off; off >>= 1) m = fmaxf(m, __shfl_xor(m, off));
    float e = expf(l - m);
    float s = e;
    for (int off = 32; off; off >>= 1) s += __shfl_xor(s, off);
    probs[((size_t)bn*PIX_ + y*FW_ + x)*D_ + c] = e / s;
}

// ---------------- geometry: cell for point i (f32 chain, validated r4) ------
__device__ __forceinline__ int compute_cell(int i, const float* __restrict__ kinv,
                                            const float* __restrict__ ext) {
#pragma clang fp contract(off)
    int x  = i % FW_;
    int y  = (i / FW_) % FH_;
    int d  = (i / PIX_) % D_;
    int bn = i / PPBN;

    const float* kv = kinv + bn*9;
    const float* e  = ext  + bn*16;

    float u  = (x == FW_-1) ? 703.0f : (float)((double)x * (703.0/43.0));
    float vv = (float)((double)y * 17.0);
    float dd = (d == D_-1) ? 60.0f  : (float)(1.0 + (double)d * (59.0/63.0));

    float px = u * dd;
    float py = vv * dd;
    float pz = dd;

    float cx = (kv[0]*px + kv[1]*py) + kv[2]*pz;
    float cy = (kv[3]*px + kv[4]*py) + kv[5]*pz;
    float cz = (kv[6]*px + kv[7]*py) + kv[8]*pz;

    float ex = (e[0]*cx + e[1]*cy) + e[2]*cz;
    float ey = (e[4]*cx + e[5]*cy) + e[6]*cz;
    ex = ex + e[3];
    ey = ey + e[7];

    float gx = (ex + 50.0f) / 0.5f;
    float gy = (ey + 50.0f) / 0.5f;
    int ix = (int)floorf(gx);
    int iy = (int)floorf(gy);
    return (ix >= 0 && ix < BEVW && iy >= 0 && iy < BEVH) ? (iy*BEVW + ix) : -1;
}

// ---------------- geom + histogram ----------------
__global__ __launch_bounds__(256) void geomhist_kernel(
        const float* __restrict__ ext, const float* __restrict__ kinv,
        int* __restrict__ counts) {
    int i = blockIdx.x * blockDim.x + threadIdx.x;
    if (i >= NPTS) return;
    int cell = compute_cell(i, kinv, ext);
    if (cell < 0) return;
    int b = i / (PPBN * N_);
    atomicAdd(&counts[b*NCELL + cell], 1);
}

// ---------------- exclusive scan over NBCELL counters (single block) -------
__global__ __launch_bounds__(1024) void scan_kernel(
        int* __restrict__ startp, int* __restrict__ cursor) {
    __shared__ int sdata[1024];
    const int CH = (NBCELL + 1023) / 1024;   // 79
    int t  = threadIdx.x;
    int k0 = t * CH;
    int k1 = min(k0 + CH, NBCELL);
    int local = 0;
    for (int k = k0; k < k1; k++) local += startp[1 + k];
    sdata[t] = local;
    __syncthreads();
    for (int off = 1; off < 1024; off <<= 1) {
        int add = (t >= off) ? sdata[t - off] : 0;
        __syncthreads();
        sdata[t] += add;
        __syncthreads();
    }
    int running = (t == 0) ? 0 : sdata[t - 1];
    for (int k = k0; k < k1; k++) {
        int cnt = startp[1 + k];
        cursor[k] = running;
        running += cnt;
        startp[1 + k] = running;
    }
}

// ---------------- geom + scatter packed records ----------------
// record: .x = prob bits, .y = pixg | (cell_local << 16)
__global__ __launch_bounds__(256) void geomscatter_kernel(
        const float* __restrict__ ext, const float* __restrict__ kinv,
        const float* __restrict__ probs,
        int* __restrict__ cursor, int2* __restrict__ plist2) {
    int i = blockIdx.x * blockDim.x + threadIdx.x;
    if (i >= NPTS) return;
    int cell = compute_cell(i, kinv, ext);
    if (cell < 0) return;
    int pix = i % PIX_;
    int d   = (i / PIX_) % D_;
    int bn  = i / PPBN;
    int b   = bn / N_;
    int pixg = bn*PIX_ + pix;
    float pr = probs[(size_t)pixg*D_ + d];
    int pos = atomicAdd(&cursor[b*NCELL + cell], 1);
    plist2[pos] = make_int2(__float_as_int(pr), pixg | ((cell & 63) << 16));
}

// ---------------- gather v2: tile = 64 consecutive cells, 16 waves ---------
__global__ __launch_bounds__(1024) void gather2_kernel(
        const float* __restrict__ feat_t,
        const int* __restrict__ startp, const int2* __restrict__ plist2,
        float* __restrict__ out) {
    __shared__ float acc_s[64][65];
    int blk  = blockIdx.x;                 // 0..NTILE-1
    int b    = blk / (NCELL/64);           // 625 tiles per batch
    int cb   = (blk % (NCELL/64)) * 64;
    int t    = threadIdx.x;
    int lane = t & 63;
    int w    = __builtin_amdgcn_readfirstlane(t >> 6);   // wave id 0..15

    for (int idx = t; idx < 64*65; idx += 1024)
        ((float*)acc_s)[idx] = 0.f;
    __syncthreads();

    int fc0 = b*NCELL + cb;
    int s0  = startp[fc0];
    int e0  = startp[fc0 + 64];
    int n   = e0 - s0;
    int per = (n + 15) >> 4;
    int ps  = s0 + w * per;
    int pe  = min(ps + per, e0);

    float acc = 0.f;
    int   cur = -1;
    for (int p = ps; p < pe; p++) {
        int2 r = plist2[p];
        int cl = r.y >> 16;
        if (cl != cur) {
            if (cur >= 0) atomicAdd(&acc_s[cur][lane], acc);
            acc = 0.f; cur = cl;
        }
        acc = fmaf(__int_as_float(r.x),
                   feat_t[(size_t)(r.y & 0xFFFF)*C_ + lane], acc);
    }
    if (cur >= 0) atomicAdd(&acc_s[cur][lane], acc);
    __syncthreads();

#pragma unroll
    for (int rr = 0; rr < 4; rr++) {
        int cidx = (w << 2) + rr;
        out[((size_t)b*C_ + cidx)*NCELL + cb + lane] = acc_s[lane][cidx];
    }
}

extern "C" void kernel_launch(void* const* d_in, const int* in_sizes, int n_in,
                              void* d_out, int out_size, void* d_ws, size_t ws_size,
                              hipStream_t stream) {
    const float* feat  = (const float*)d_in[0];
    const float* intr  = (const float*)d_in[1];
    const float* ext   = (const float*)d_in[2];
    const float* w1    = (const float*)d_in[3];
    const float* b1    = (const float*)d_in[4];
    const float* gamma = (const float*)d_in[5];
    const float* beta  = (const float*)d_in[6];
    const float* rmean = (const float*)d_in[7];
    const float* rvar  = (const float*)d_in[8];
    const float* w2    = (const float*)d_in[9];
    const float* b2    = (const float*)d_in[10];
    float* out = (float*)d_out;
    (void)in_sizes; (void)n_in; (void)out_size; (void)ws_size;

    // workspace layout (plist2 first for 8B alignment); total ~9.5 MB
    int2*  plist2 = (int2*)d_ws;                    // NPTS int2 = 4.33 MB
    float* w1t    = (float*)(plist2 + NPTS);        // 36864
    float* w2t    = w1t + C_*C_*9;                  // 4096
    float* bns    = w2t + D_*C_;                    // 64
    float* bnsh   = bns + C_;                       // 64
    float* kinv   = bnsh + C_;                      // 108
    float* probs  = kinv + BN_*9;                   // 540672
    float* feat_t = probs + NPTS;                   // 540672
    int*   startp = (int*)(feat_t + NPTS);          // 80001
    int*   cursor = startp + (NBCELL + 1);          // 80000

    // ---- sorted-gather pipeline (no output atomics, balanced gather) ----
    int nz = NBCELL + 1 + NBCELL;   // startp + cursor (contiguous)
    zero_i_kernel<<<(nz + 255)/256, 256, 0, stream>>>(startp, nz);
    prep_kernel<<<1, 256, 0, stream>>>(w1, w2, gamma, beta, rmean, rvar, intr,
                                       w1t, w2t, bns, bnsh, kinv);
    featT_kernel<<<NPIX/64, 256, 0, stream>>>(feat, feat_t);
    enc_kernel<<<BN_*FH_*11, 256, 0, stream>>>(feat, w1t, w2t, bns, bnsh, b1, b2, probs);
    geomhist_kernel<<<NPTS/256, 256, 0, stream>>>(ext, kinv, startp + 1);
    scan_kernel<<<1, 1024, 0, stream>>>(startp, cursor);
    geomscatter_kernel<<<NPTS/256, 256, 0, stream>>>(ext, kinv, probs, cursor, plist2);
    gather2_kernel<<<NTILE, 1024, 0, stream>>>(feat_t, startp, plist2, out);
}

// Round 8
// 563.325 us; speedup vs baseline: 4.5415x; 1.3046x over previous
//
#include <hip/hip_runtime.h>
#include <math.h>

#define B_   2
#define N_   6
#define C_   64
#define D_   64
#define FH_  16
#define FW_  44
#define BN_  (B_*N_)              // 12
#define PIX_ (FH_*FW_)            // 704
#define NPIX (BN_*PIX_)           // 8448
#define NPTS (BN_*D_*PIX_)        // 540672
#define PPBN (D_*PIX_)            // 45056 points per (b,n) image
#define BEVH 200
#define BEVW 200
#define NCELL (BEVH*BEVW)         // 40000
#define NBCELL (B_*NCELL)         // 80000
#define NTILE (NBCELL/64)         // 1250 tiles of 64 consecutive cells
#define NSCANB ((NBCELL + 255)/256)  // 313 scan blocks

// ---------------- zero helper ----------------
__global__ void zero_i_kernel(int* __restrict__ p, int n) {
    int i = blockIdx.x * blockDim.x + threadIdx.x;
    if (i < n) p[i] = 0;
}

// ---------------- prep: transpose weights, BN affine, Kinv ----------------
// Kinv emulates numpy/LAPACK f32 inverse (sgetf2 + strti2 + sgetri).
__global__ __launch_bounds__(256) void prep_kernel(
        const float* __restrict__ w1, const float* __restrict__ w2,
        const float* __restrict__ gamma, const float* __restrict__ beta,
        const float* __restrict__ rmean, const float* __restrict__ rvar,
        const float* __restrict__ intr,
        float* __restrict__ w1t, float* __restrict__ w2t,
        float* __restrict__ bns, float* __restrict__ bnsh,
        float* __restrict__ kinv) {
#pragma clang fp contract(off)
    int t = threadIdx.x;
    for (int idx = t; idx < C_*C_*9; idx += 256) {
        int cout = idx / (C_*9);
        int r    = idx % (C_*9);
        w1t[r*C_ + cout] = w1[idx];
    }
    for (int idx = t; idx < D_*C_; idx += 256) {
        int d = idx / C_, c = idx % C_;
        w2t[c*D_ + d] = w2[idx];
    }
    if (t < C_) {
        float s = gamma[t] / sqrtf(rvar[t] + 1e-5f);
        bns[t]  = s;
        bnsh[t] = beta[t] - rmean[t] * s;
    }
    if (t < BN_) {
        const float* K = intr + t*9;
        float A[3][3];
        for (int r = 0; r < 3; r++)
            for (int cc = 0; cc < 3; cc++) A[r][cc] = K[r*3 + cc];
        int ipiv[3];
        for (int j = 0; j < 3; j++) {
            int p = j; float mx = fabsf(A[j][j]);
            for (int i = j+1; i < 3; i++) {
                float v = fabsf(A[i][j]);
                if (v > mx) { mx = v; p = i; }
            }
            ipiv[j] = p;
            if (p != j)
                for (int k = 0; k < 3; k++) { float tm = A[j][k]; A[j][k] = A[p][k]; A[p][k] = tm; }
            float rpiv = 1.0f / A[j][j];
            for (int i = j+1; i < 3; i++) A[i][j] = A[i][j] * rpiv;
            for (int k = j+1; k < 3; k++)
                for (int i = j+1; i < 3; i++)
                    A[i][k] = A[i][k] - A[i][j] * A[j][k];
        }
        for (int j = 0; j < 3; j++) {
            float ajj = 1.0f / A[j][j];
            A[j][j] = ajj;
            float najj = -ajj;
            for (int jj = 0; jj < j; jj++) {
                float temp = A[jj][j];
                for (int i = 0; i < jj; i++) A[i][j] = A[i][j] + temp * A[i][jj];
                A[jj][j] = A[jj][j] * A[jj][jj];
            }
            for (int i = 0; i < j; i++) A[i][j] = A[i][j] * najj;
        }
        for (int j = 1; j >= 0; j--) {
            float work[3];
            for (int i = j+1; i < 3; i++) { work[i] = A[i][j]; A[i][j] = 0.0f; }
            for (int k = j+1; k < 3; k++)
                for (int i = 0; i < 3; i++)
                    A[i][j] = A[i][j] - A[i][k] * work[k];
        }
        for (int j = 2; j >= 0; j--) {
            int p = ipiv[j];
            if (p != j)
                for (int i = 0; i < 3; i++) { float tm = A[i][j]; A[i][j] = A[i][p]; A[i][p] = tm; }
        }
        for (int k = 0; k < 9; k++) kinv[t*9 + k] = A[k/3][k%3];
    }
}

// ---------------- feat transpose: [bn][c][pix] -> [bn*704+pix][c] ----------------
__global__ __launch_bounds__(256) void featT_kernel(
        const float* __restrict__ feat, float* __restrict__ feat_t) {
    __shared__ float lds[64][65];
    int j    = blockIdx.x;
    int bn   = j / 11;
    int pb   = (j % 11) * 64;
    int t    = threadIdx.x;
    int lane = t & 63;
    int r0   = t >> 6;
#pragma unroll
    for (int rr = 0; rr < 16; rr++) {
        int c = r0 + 4*rr;
        lds[c][lane] = feat[((size_t)bn*C_ + c)*PIX_ + pb + lane];
    }
    __syncthreads();
#pragma unroll
    for (int rr = 0; rr < 16; rr++) {
        int pr = r0 + 4*rr;
        feat_t[((size_t)bn*PIX_ + pb + pr)*C_ + lane] = lds[lane][pr];
    }
}

// ---------------- fused conv3x3+BN+ReLU+conv1x1+softmax, 1 wave = 1 pixel --
__global__ __launch_bounds__(256) void enc_kernel(
        const float* __restrict__ feat,
        const float* __restrict__ w1t, const float* __restrict__ w2t,
        const float* __restrict__ bns, const float* __restrict__ bnsh,
        const float* __restrict__ b1,  const float* __restrict__ b2,
        float* __restrict__ probs) {
    __shared__ float hl[4][C_];
    int blk = blockIdx.x;               // 0..2111
    int bn  = blk / (FH_*11);
    int rem = blk % (FH_*11);
    int y   = rem / 11;
    int t   = threadIdx.x;
    int c   = t & 63;
    int w   = __builtin_amdgcn_readfirstlane(t >> 6);   // wave id 0..3
    int x   = (rem % 11) * 4 + w;       // pixel for this wave

    float h = b1[c];
    const float* fbn = feat + (size_t)bn * C_ * PIX_;
    for (int ci = 0; ci < C_; ci++) {
        const float* fc   = fbn + ci * PIX_;
        const float* wrow = w1t + ci * 9 * C_;
#pragma unroll
        for (int ky = 0; ky < 3; ky++) {
            int iy2 = y + ky - 1;
            if (iy2 < 0 || iy2 >= FH_) continue;
            const float* frow = fc + iy2 * FW_;
#pragma unroll
            for (int kx = 0; kx < 3; kx++) {
                int xs = x + kx - 1;
                if (xs < 0 || xs >= FW_) continue;
                h = fmaf(wrow[(ky*3 + kx)*C_ + c], frow[xs], h);
            }
        }
    }
    float v = fmaf(h, bns[c], bnsh[c]);
    hl[w][c] = v > 0.f ? v : 0.f;
    __syncthreads();

    float l = b2[c];
    for (int c2 = 0; c2 < C_; c2++)
        l = fmaf(w2t[c2*D_ + c], hl[w][c2], l);

    float m = l;
    for (int off = 32; off; off >>= 1) m = fmaxf(m, __shfl_xor(m, off));
    float e = expf(l - m);
    float s = e;
    for (int off = 32; off; off >>= 1) s += __shfl_xor(s, off);
    probs[((size_t)bn*PIX_ + y*FW_ + x)*D_ + c] = e / s;
}

// ---------------- geometry: cell for point i (f32 chain, validated r4) ------
__device__ __forceinline__ int compute_cell(int i, const float* __restrict__ kinv,
                                            const float* __restrict__ ext) {
#pragma clang fp contract(off)
    int x  = i % FW_;
    int y  = (i / FW_) % FH_;
    int d  = (i / PIX_) % D_;
    int bn = i / PPBN;

    const float* kv = kinv + bn*9;
    const float* e  = ext  + bn*16;

    float u  = (x == FW_-1) ? 703.0f : (float)((double)x * (703.0/43.0));
    float vv = (float)((double)y * 17.0);
    float dd = (d == D_-1) ? 60.0f  : (float)(1.0 + (double)d * (59.0/63.0));

    float px = u * dd;
    float py = vv * dd;
    float pz = dd;

    float cx = (kv[0]*px + kv[1]*py) + kv[2]*pz;
    float cy = (kv[3]*px + kv[4]*py) + kv[5]*pz;
    float cz = (kv[6]*px + kv[7]*py) + kv[8]*pz;

    float ex = (e[0]*cx + e[1]*cy) + e[2]*cz;
    float ey = (e[4]*cx + e[5]*cy) + e[6]*cz;
    ex = ex + e[3];
    ey = ey + e[7];

    float gx = (ex + 50.0f) / 0.5f;
    float gy = (ey + 50.0f) / 0.5f;
    int ix = (int)floorf(gx);
    int iy = (int)floorf(gy);
    return (ix >= 0 && ix < BEVW && iy >= 0 && iy < BEVH) ? (iy*BEVW + ix) : -1;
}

// ---------------- geom + histogram ----------------
__global__ __launch_bounds__(256) void geomhist_kernel(
        const float* __restrict__ ext, const float* __restrict__ kinv,
        int* __restrict__ counts) {
    int i = blockIdx.x * blockDim.x + threadIdx.x;
    if (i >= NPTS) return;
    int cell = compute_cell(i, kinv, ext);
    if (cell < 0) return;
    int b = i / (PPBN * N_);
    atomicAdd(&counts[b*NCELL + cell], 1);
}

// ---------------- 3-phase parallel scan over NBCELL counters ----------------
// A: block-local scan of 256 counts -> startp[1+i]=local incl, cursor[i]=local
//    excl, bsum[blk]=total.   B: scan the 313 block totals.   C: add offsets.
__global__ __launch_bounds__(256) void scanA_kernel(
        int* __restrict__ startp, int* __restrict__ cursor, int* __restrict__ bsum) {
    __shared__ int sdata[256];
    int t = threadIdx.x;
    int i = blockIdx.x * 256 + t;
    int v = (i < NBCELL) ? startp[1 + i] : 0;
    sdata[t] = v;
    __syncthreads();
#pragma unroll
    for (int off = 1; off < 256; off <<= 1) {
        int add = (t >= off) ? sdata[t - off] : 0;
        __syncthreads();
        sdata[t] += add;
        __syncthreads();
    }
    if (i < NBCELL) {
        startp[1 + i] = sdata[t];          // local inclusive
        cursor[i]     = sdata[t] - v;      // local exclusive
    }
    if (t == 255) bsum[blockIdx.x] = sdata[255];
}

__global__ __launch_bounds__(512) void scanB_kernel(int* __restrict__ bsum) {
    __shared__ int sdata[512];
    int t = threadIdx.x;
    int v = (t < NSCANB) ? bsum[t] : 0;
    sdata[t] = v;
    __syncthreads();
#pragma unroll
    for (int off = 1; off < 512; off <<= 1) {
        int add = (t >= off) ? sdata[t - off] : 0;
        __syncthreads();
        sdata[t] += add;
        __syncthreads();
    }
    if (t < NSCANB) bsum[t] = sdata[t] - v;   // exclusive block offset
}

__global__ __launch_bounds__(256) void scanC_kernel(
        int* __restrict__ startp, int* __restrict__ cursor,
        const int* __restrict__ bsum) {
    int blk = blockIdx.x;
    int t   = threadIdx.x;
    int i   = blk * 256 + t;
    if (i >= NBCELL) return;
    int off = bsum[blk];
    startp[1 + i] += off;
    cursor[i]     += off;
}

// ---------------- geom + scatter packed records ----------------
// record: .x = prob bits, .y = pixg | (cell_local << 16)
__global__ __launch_bounds__(256) void geomscatter_kernel(
        const float* __restrict__ ext, const float* __restrict__ kinv,
        const float* __restrict__ probs,
        int* __restrict__ cursor, int2* __restrict__ plist2) {
    int i = blockIdx.x * blockDim.x + threadIdx.x;
    if (i >= NPTS) return;
    int cell = compute_cell(i, kinv, ext);
    if (cell < 0) return;
    int pix = i % PIX_;
    int d   = (i / PIX_) % D_;
    int bn  = i / PPBN;
    int b   = bn / N_;
    int pixg = bn*PIX_ + pix;
    float pr = probs[(size_t)pixg*D_ + d];
    int pos = atomicAdd(&cursor[b*NCELL + cell], 1);
    plist2[pos] = make_int2(__float_as_int(pr), pixg | ((cell & 63) << 16));
}

// ---------------- gather v2: tile = 64 consecutive cells, 16 waves ---------
__global__ __launch_bounds__(1024) void gather2_kernel(
        const float* __restrict__ feat_t,
        const int* __restrict__ startp, const int2* __restrict__ plist2,
        float* __restrict__ out) {
    __shared__ float acc_s[64][65];
    int blk  = blockIdx.x;                 // 0..NTILE-1
    int b    = blk / (NCELL/64);           // 625 tiles per batch
    int cb   = (blk % (NCELL/64)) * 64;
    int t    = threadIdx.x;
    int lane = t & 63;
    int w    = __builtin_amdgcn_readfirstlane(t >> 6);   // wave id 0..15

    for (int idx = t; idx < 64*65; idx += 1024)
        ((float*)acc_s)[idx] = 0.f;
    __syncthreads();

    int fc0 = b*NCELL + cb;
    int s0  = startp[fc0];
    int e0  = startp[fc0 + 64];
    int n   = e0 - s0;
    int per = (n + 15) >> 4;
    int ps  = s0 + w * per;
    int pe  = min(ps + per, e0);

    float acc = 0.f;
    int   cur = -1;
    for (int p = ps; p < pe; p++) {
        int2 r = plist2[p];
        int cl = r.y >> 16;
        if (cl != cur) {
            if (cur >= 0) atomicAdd(&acc_s[cur][lane], acc);
            acc = 0.f; cur = cl;
        }
        acc = fmaf(__int_as_float(r.x),
                   feat_t[(size_t)(r.y & 0xFFFF)*C_ + lane], acc);
    }
    if (cur >= 0) atomicAdd(&acc_s[cur][lane], acc);
    __syncthreads();

#pragma unroll
    for (int rr = 0; rr < 4; rr++) {
        int cidx = (w << 2) + rr;
        out[((size_t)b*C_ + cidx)*NCELL + cb + lane] = acc_s[lane][cidx];
    }
}

extern "C" void kernel_launch(void* const* d_in, const int* in_sizes, int n_in,
                              void* d_out, int out_size, void* d_ws, size_t ws_size,
                              hipStream_t stream) {
    const float* feat  = (const float*)d_in[0];
    const float* intr  = (const float*)d_in[1];
    const float* ext   = (const float*)d_in[2];
    const float* w1    = (const float*)d_in[3];
    const float* b1    = (const float*)d_in[4];
    const float* gamma = (const float*)d_in[5];
    const float* beta  = (const float*)d_in[6];
    const float* rmean = (const float*)d_in[7];
    const float* rvar  = (const float*)d_in[8];
    const float* w2    = (const float*)d_in[9];
    const float* b2    = (const float*)d_in[10];
    float* out = (float*)d_out;
    (void)in_sizes; (void)n_in; (void)out_size; (void)ws_size;

    // workspace layout (plist2 first for 8B alignment); total ~9.5 MB
    int2*  plist2 = (int2*)d_ws;                    // NPTS int2 = 4.33 MB
    float* w1t    = (float*)(plist2 + NPTS);        // 36864
    float* w2t    = w1t + C_*C_*9;                  // 4096
    float* bns    = w2t + D_*C_;                    // 64
    float* bnsh   = bns + C_;                       // 64
    float* kinv   = bnsh + C_;                      // 108
    float* probs  = kinv + BN_*9;                   // 540672
    float* feat_t = probs + NPTS;                   // 540672
    int*   startp = (int*)(feat_t + NPTS);          // 80001
    int*   cursor = startp + (NBCELL + 1);          // 80000
    int*   bsum   = cursor + NBCELL;                // 313

    // ---- sorted-gather pipeline ----
    zero_i_kernel<<<(NBCELL + 256)/256, 256, 0, stream>>>(startp, NBCELL + 1);
    prep_kernel<<<1, 256, 0, stream>>>(w1, w2, gamma, beta, rmean, rvar, intr,
                                       w1t, w2t, bns, bnsh, kinv);
    featT_kernel<<<NPIX/64, 256, 0, stream>>>(feat, feat_t);
    enc_kernel<<<BN_*FH_*11, 256, 0, stream>>>(feat, w1t, w2t, bns, bnsh, b1, b2, probs);
    geomhist_kernel<<<NPTS/256, 256, 0, stream>>>(ext, kinv, startp + 1);
    scanA_kernel<<<NSCANB, 256, 0, stream>>>(startp, cursor, bsum);
    scanB_kernel<<<1, 512, 0, stream>>>(bsum);
    scanC_kernel<<<NSCANB, 256, 0, stream>>>(startp, cursor, bsum);
    geomscatter_kernel<<<NPTS/256, 256, 0, stream>>>(ext, kinv, probs, cursor, plist2);
    gather2_kernel<<<NTILE, 1024, 0, stream>>>(feat_t, startp, plist2, out);
}

// Round 9
// 467.072 us; speedup vs baseline: 5.4773x; 1.2061x over previous
//
#include <hip/hip_runtime.h>
#include <math.h>

#define B_   2
#define N_   6
#define C_   64
#define D_   64
#define FH_  16
#define FW_  44
#define BN_  (B_*N_)              // 12
#define PIX_ (FH_*FW_)            // 704
#define NPIX (BN_*PIX_)           // 8448
#define NPTS (BN_*D_*PIX_)        // 540672
#define PPBN (D_*PIX_)            // 45056 points per (b,n) image
#define BEVH 200
#define BEVW 200
#define NCELL (BEVH*BEVW)         // 40000
#define NBCELL (B_*NCELL)         // 80000
#define NTILE (NBCELL/64)         // 1250 tiles of 64 consecutive cells
#define NSCANB ((NBCELL + 255)/256)  // 313 scan blocks

// ---------------- zero helper ----------------
__global__ void zero_i_kernel(int* __restrict__ p, int n) {
    int i = blockIdx.x * blockDim.x + threadIdx.x;
    if (i < n) p[i] = 0;
}

// ---------------- weight transposes (parallel) ----------------
// w1 (cout,cin,3,3) -> w1t[(cin*9+tap)*64 + cout]; w2 (d,c) -> w2t[c*64 + d]
__global__ __launch_bounds__(256) void transW_kernel(
        const float* __restrict__ w1, const float* __restrict__ w2,
        float* __restrict__ w1t, float* __restrict__ w2t) {
    int idx = blockIdx.x * 256 + threadIdx.x;
    if (idx < C_*C_*9) {
        int cout = idx / (C_*9);
        int r    = idx % (C_*9);
        w1t[r*C_ + cout] = w1[idx];
    } else if (idx < C_*C_*9 + D_*C_) {
        int j = idx - C_*C_*9;
        int d = j / C_, c = j % C_;
        w2t[c*D_ + d] = w2[j];
    }
}

// ---------------- small prep: BN affine + LAPACK-f32 Kinv ----------------
__global__ __launch_bounds__(64) void prep_small_kernel(
        const float* __restrict__ gamma, const float* __restrict__ beta,
        const float* __restrict__ rmean, const float* __restrict__ rvar,
        const float* __restrict__ intr,
        float* __restrict__ bns, float* __restrict__ bnsh,
        float* __restrict__ kinv) {
#pragma clang fp contract(off)
    int t = threadIdx.x;
    if (t < C_) {
        float s = gamma[t] / sqrtf(rvar[t] + 1e-5f);
        bns[t]  = s;
        bnsh[t] = beta[t] - rmean[t] * s;
    }
    if (t < BN_) {
        const float* K = intr + t*9;
        float A[3][3];
        for (int r = 0; r < 3; r++)
            for (int cc = 0; cc < 3; cc++) A[r][cc] = K[r*3 + cc];
        int ipiv[3];
        for (int j = 0; j < 3; j++) {
            int p = j; float mx = fabsf(A[j][j]);
            for (int i = j+1; i < 3; i++) {
                float v = fabsf(A[i][j]);
                if (v > mx) { mx = v; p = i; }
            }
            ipiv[j] = p;
            if (p != j)
                for (int k = 0; k < 3; k++) { float tm = A[j][k]; A[j][k] = A[p][k]; A[p][k] = tm; }
            float rpiv = 1.0f / A[j][j];
            for (int i = j+1; i < 3; i++) A[i][j] = A[i][j] * rpiv;
            for (int k = j+1; k < 3; k++)
                for (int i = j+1; i < 3; i++)
                    A[i][k] = A[i][k] - A[i][j] * A[j][k];
        }
        for (int j = 0; j < 3; j++) {
            float ajj = 1.0f / A[j][j];
            A[j][j] = ajj;
            float najj = -ajj;
            for (int jj = 0; jj < j; jj++) {
                float temp = A[jj][j];
                for (int i = 0; i < jj; i++) A[i][j] = A[i][j] + temp * A[i][jj];
                A[jj][j] = A[jj][j] * A[jj][jj];
            }
            for (int i = 0; i < j; i++) A[i][j] = A[i][j] * najj;
        }
        for (int j = 1; j >= 0; j--) {
            float work[3];
            for (int i = j+1; i < 3; i++) { work[i] = A[i][j]; A[i][j] = 0.0f; }
            for (int k = j+1; k < 3; k++)
                for (int i = 0; i < 3; i++)
                    A[i][j] = A[i][j] - A[i][k] * work[k];
        }
        for (int j = 2; j >= 0; j--) {
            int p = ipiv[j];
            if (p != j)
                for (int i = 0; i < 3; i++) { float tm = A[i][j]; A[i][j] = A[i][p]; A[i][p] = tm; }
        }
        for (int k = 0; k < 9; k++) kinv[t*9 + k] = A[k/3][k%3];
    }
}

// ---------------- feat transpose: [bn][c][pix] -> [bn*704+pix][c] ----------------
__global__ __launch_bounds__(256) void featT_kernel(
        const float* __restrict__ feat, float* __restrict__ feat_t) {
    __shared__ float lds[64][65];
    int j    = blockIdx.x;
    int bn   = j / 11;
    int pb   = (j % 11) * 64;
    int t    = threadIdx.x;
    int lane = t & 63;
    int r0   = t >> 6;
#pragma unroll
    for (int rr = 0; rr < 16; rr++) {
        int c = r0 + 4*rr;
        lds[c][lane] = feat[((size_t)bn*C_ + c)*PIX_ + pb + lane];
    }
    __syncthreads();
#pragma unroll
    for (int rr = 0; rr < 16; rr++) {
        int pr = r0 + 4*rr;
        feat_t[((size_t)bn*PIX_ + pb + pr)*C_ + lane] = lds[lane][pr];
    }
}

// ---------------- enc v3: LDS-staged weights, 4 pixels/wave -----------------
// grid = 12 bn x 4 ytile x 11 xtile = 528 blocks; 256 threads = 4 waves.
// wave w handles row y = yt*4+w, pixels x0..x0+3; lane = cout then depth bin.
// fp op order identical to prior rounds: ci asc, ky, kx, fmaf chain per pixel.
__global__ __launch_bounds__(256) void enc_kernel(
        const float* __restrict__ feat,
        const float* __restrict__ w1t, const float* __restrict__ w2t,
        const float* __restrict__ bns, const float* __restrict__ bnsh,
        const float* __restrict__ b1,  const float* __restrict__ b2,
        float* __restrict__ probs) {
    __shared__ float wlds[16*9*C_];    // 36 KB: one 16-ci chunk of w1t
    __shared__ float hl[16][C_];       // 4 KB: relu outputs, row-major pixel x chan
    int blk = blockIdx.x;              // 0..527
    int bn  = blk / 44;
    int rem = blk % 44;
    int yt  = rem / 11;
    int xt  = rem % 11;
    int t   = threadIdx.x;
    int c   = t & 63;
    int w   = __builtin_amdgcn_readfirstlane(t >> 6);   // wave id 0..3
    int y   = yt*4 + w;
    int x0  = xt*4;

    float h0 = b1[c], h1 = h0, h2 = h0, h3 = h0;
    const float* fbn = feat + (size_t)bn * C_ * PIX_;

    for (int cc = 0; cc < C_; cc += 16) {
        __syncthreads();
        // stage 16-ci chunk (contiguous 36 KB) via float4
        {
            const float4* s4 = (const float4*)(w1t + cc*9*C_);
            float4* d4 = (float4*)wlds;
#pragma unroll
            for (int i = 0; i < 9; i++)
                d4[t + 256*i] = s4[t + 256*i];
        }
        __syncthreads();
        for (int ci = 0; ci < 16; ci++) {
            const float* fc = fbn + (cc + ci) * PIX_;
            const float* wl = wlds + ci*9*C_;
#pragma unroll
            for (int ky = 0; ky < 3; ky++) {
                int iy2 = y + ky - 1;
                if (iy2 < 0 || iy2 >= FH_) continue;     // wave-uniform
                const float* frow = fc + iy2 * FW_;
#pragma unroll
                for (int kx = 0; kx < 3; kx++) {
                    float wv = wl[(ky*3 + kx)*C_ + c];   // LDS, stride-1
                    int xs = x0 + kx - 1;
                    if (xs >= 0)       h0 = fmaf(wv, frow[xs],     h0);
                    h1 = fmaf(wv, frow[xs + 1], h1);
                    h2 = fmaf(wv, frow[xs + 2], h2);
                    if (xs + 3 < FW_)  h3 = fmaf(wv, frow[xs + 3], h3);
                }
            }
        }
    }

    // BN + ReLU -> hl
    float sc = bns[c], sh = bnsh[c];
    {
        float v0 = fmaf(h0, sc, sh); hl[w*4 + 0][c] = v0 > 0.f ? v0 : 0.f;
        float v1 = fmaf(h1, sc, sh); hl[w*4 + 1][c] = v1 > 0.f ? v1 : 0.f;
        float v2 = fmaf(h2, sc, sh); hl[w*4 + 2][c] = v2 > 0.f ? v2 : 0.f;
        float v3 = fmaf(h3, sc, sh); hl[w*4 + 3][c] = v3 > 0.f ? v3 : 0.f;
    }
    __syncthreads();

    // conv2 (1x1): lane = depth bin d
    float l0 = b2[c], l1 = l0, l2 = l0, l3 = l0;
    for (int c2 = 0; c2 < C_; c2++) {
        float wv = w2t[c2*D_ + c];
        l0 = fmaf(wv, hl[w*4 + 0][c2], l0);
        l1 = fmaf(wv, hl[w*4 + 1][c2], l1);
        l2 = fmaf(wv, hl[w*4 + 2][c2], l2);
        l3 = fmaf(wv, hl[w*4 + 3][c2], l3);
    }

    // softmax over the 64 lanes, one pixel at a time (order as before)
    float lv[4] = {l0, l1, l2, l3};
#pragma unroll
    for (int p = 0; p < 4; p++) {
        float l = lv[p];
        float m = l;
        for (int off = 32; off; off >>= 1) m = fmaxf(m, __shfl_xor(m, off));
        float e = expf(l - m);
        float s = e;
        for (int off = 32; off; off >>= 1) s += __shfl_xor(s, off);
        probs[((size_t)bn*PIX_ + y*FW_ + x0 + p)*D_ + c] = e / s;
    }
}

// ---------------- geometry: cell for point i (f32 chain, validated r4) ------
__device__ __forceinline__ int compute_cell(int i, const float* __restrict__ kinv,
                                            const float* __restrict__ ext) {
#pragma clang fp contract(off)
    int x  = i % FW_;
    int y  = (i / FW_) % FH_;
    int d  = (i / PIX_) % D_;
    int bn = i / PPBN;

    const float* kv = kinv + bn*9;
    const float* e  = ext  + bn*16;

    float u  = (x == FW_-1) ? 703.0f : (float)((double)x * (703.0/43.0));
    float vv = (float)((double)y * 17.0);
    float dd = (d == D_-1) ? 60.0f  : (float)(1.0 + (double)d * (59.0/63.0));

    float px = u * dd;
    float py = vv * dd;
    float pz = dd;

    float cx = (kv[0]*px + kv[1]*py) + kv[2]*pz;
    float cy = (kv[3]*px + kv[4]*py) + kv[5]*pz;
    float cz = (kv[6]*px + kv[7]*py) + kv[8]*pz;

    float ex = (e[0]*cx + e[1]*cy) + e[2]*cz;
    float ey = (e[4]*cx + e[5]*cy) + e[6]*cz;
    ex = ex + e[3];
    ey = ey + e[7];

    float gx = (ex + 50.0f) / 0.5f;
    float gy = (ey + 50.0f) / 0.5f;
    int ix = (int)floorf(gx);
    int iy = (int)floorf(gy);
    return (ix >= 0 && ix < BEVW && iy >= 0 && iy < BEVH) ? (iy*BEVW + ix) : -1;
}

// ---------------- geom + histogram ----------------
__global__ __launch_bounds__(256) void geomhist_kernel(
        const float* __restrict__ ext, const float* __restrict__ kinv,
        int* __restrict__ counts) {
    int i = blockIdx.x * blockDim.x + threadIdx.x;
    if (i >= NPTS) return;
    int cell = compute_cell(i, kinv, ext);
    if (cell < 0) return;
    int b = i / (PPBN * N_);
    atomicAdd(&counts[b*NCELL + cell], 1);
}

// ---------------- 3-phase parallel scan over NBCELL counters ----------------
__global__ __launch_bounds__(256) void scanA_kernel(
        int* __restrict__ startp, int* __restrict__ cursor, int* __restrict__ bsum) {
    __shared__ int sdata[256];
    int t = threadIdx.x;
    int i = blockIdx.x * 256 + t;
    int v = (i < NBCELL) ? startp[1 + i] : 0;
    sdata[t] = v;
    __syncthreads();
#pragma unroll
    for (int off = 1; off < 256; off <<= 1) {
        int add = (t >= off) ? sdata[t - off] : 0;
        __syncthreads();
        sdata[t] += add;
        __syncthreads();
    }
    if (i < NBCELL) {
        startp[1 + i] = sdata[t];          // local inclusive
        cursor[i]     = sdata[t] - v;      // local exclusive
    }
    if (t == 255) bsum[blockIdx.x] = sdata[255];
}

__global__ __launch_bounds__(512) void scanB_kernel(int* __restrict__ bsum) {
    __shared__ int sdata[512];
    int t = threadIdx.x;
    int v = (t < NSCANB) ? bsum[t] : 0;
    sdata[t] = v;
    __syncthreads();
#pragma unroll
    for (int off = 1; off < 512; off <<= 1) {
        int add = (t >= off) ? sdata[t - off] : 0;
        __syncthreads();
        sdata[t] += add;
        __syncthreads();
    }
    if (t < NSCANB) bsum[t] = sdata[t] - v;   // exclusive block offset
}

__global__ __launch_bounds__(256) void scanC_kernel(
        int* __restrict__ startp, int* __restrict__ cursor,
        const int* __restrict__ bsum) {
    int blk = blockIdx.x;
    int t   = threadIdx.x;
    int i   = blk * 256 + t;
    if (i >= NBCELL) return;
    int off = bsum[blk];
    startp[1 + i] += off;
    cursor[i]     += off;
}

// ---------------- geom + scatter packed records ----------------
// record: .x = prob bits, .y = pixg | (cell_local << 16)
__global__ __launch_bounds__(256) void geomscatter_kernel(
        const float* __restrict__ ext, const float* __restrict__ kinv,
        const float* __restrict__ probs,
        int* __restrict__ cursor, int2* __restrict__ plist2) {
    int i = blockIdx.x * blockDim.x + threadIdx.x;
    if (i >= NPTS) return;
    int cell = compute_cell(i, kinv, ext);
    if (cell < 0) return;
    int pix = i % PIX_;
    int d   = (i / PIX_) % D_;
    int bn  = i / PPBN;
    int b   = bn / N_;
    int pixg = bn*PIX_ + pix;
    float pr = probs[(size_t)pixg*D_ + d];
    int pos = atomicAdd(&cursor[b*NCELL + cell], 1);
    plist2[pos] = make_int2(__float_as_int(pr), pixg | ((cell & 63) << 16));
}

// ---------------- gather v2: tile = 64 consecutive cells, 16 waves ---------
__global__ __launch_bounds__(1024) void gather2_kernel(
        const float* __restrict__ feat_t,
        const int* __restrict__ startp, const int2* __restrict__ plist2,
        float* __restrict__ out) {
    __shared__ float acc_s[64][65];
    int blk  = blockIdx.x;                 // 0..NTILE-1
    int b    = blk / (NCELL/64);           // 625 tiles per batch
    int cb   = (blk % (NCELL/64)) * 64;
    int t    = threadIdx.x;
    int lane = t & 63;
    int w    = __builtin_amdgcn_readfirstlane(t >> 6);   // wave id 0..15

    for (int idx = t; idx < 64*65; idx += 1024)
        ((float*)acc_s)[idx] = 0.f;
    __syncthreads();

    int fc0 = b*NCELL + cb;
    int s0  = startp[fc0];
    int e0  = startp[fc0 + 64];
    int n   = e0 - s0;
    int per = (n + 15) >> 4;
    int ps  = s0 + w * per;
    int pe  = min(ps + per, e0);

    float acc = 0.f;
    int   cur = -1;
    for (int p = ps; p < pe; p++) {
        int2 r = plist2[p];
        int cl = r.y >> 16;
        if (cl != cur) {
            if (cur >= 0) atomicAdd(&acc_s[cur][lane], acc);
            acc = 0.f; cur = cl;
        }
        acc = fmaf(__int_as_float(r.x),
                   feat_t[(size_t)(r.y & 0xFFFF)*C_ + lane], acc);
    }
    if (cur >= 0) atomicAdd(&acc_s[cur][lane], acc);
    __syncthreads();

#pragma unroll
    for (int rr = 0; rr < 4; rr++) {
        int cidx = (w << 2) + rr;
        out[((size_t)b*C_ + cidx)*NCELL + cb + lane] = acc_s[lane][cidx];
    }
}

extern "C" void kernel_launch(void* const* d_in, const int* in_sizes, int n_in,
                              void* d_out, int out_size, void* d_ws, size_t ws_size,
                              hipStream_t stream) {
    const float* feat  = (const float*)d_in[0];
    const float* intr  = (const float*)d_in[1];
    const float* ext   = (const float*)d_in[2];
    const float* w1    = (const float*)d_in[3];
    const float* b1    = (const float*)d_in[4];
    const float* gamma = (const float*)d_in[5];
    const float* beta  = (const float*)d_in[6];
    const float* rmean = (const float*)d_in[7];
    const float* rvar  = (const float*)d_in[8];
    const float* w2    = (const float*)d_in[9];
    const float* b2    = (const float*)d_in[10];
    float* out = (float*)d_out;
    (void)in_sizes; (void)n_in; (void)out_size; (void)ws_size;

    // workspace layout (plist2 first for 8B alignment); total ~9.5 MB
    int2*  plist2 = (int2*)d_ws;                    // NPTS int2 = 4.33 MB
    float* w1t    = (float*)(plist2 + NPTS);        // 36864
    float* w2t    = w1t + C_*C_*9;                  // 4096
    float* bns    = w2t + D_*C_;                    // 64
    float* bnsh   = bns + C_;                       // 64
    float* kinv   = bnsh + C_;                      // 108
    float* probs  = kinv + BN_*9;                   // 540672
    float* feat_t = probs + NPTS;                   // 540672
    int*   startp = (int*)(feat_t + NPTS);          // 80001
    int*   cursor = startp + (NBCELL + 1);          // 80000
    int*   bsum   = cursor + NBCELL;                // 313

    // ---- sorted-gather pipeline ----
    zero_i_kernel<<<(NBCELL + 256)/256, 256, 0, stream>>>(startp, NBCELL + 1);
    transW_kernel<<<(C_*C_*9 + D_*C_ + 255)/256, 256, 0, stream>>>(w1, w2, w1t, w2t);
    prep_small_kernel<<<1, 64, 0, stream>>>(gamma, beta, rmean, rvar, intr,
                                            bns, bnsh, kinv);
    featT_kernel<<<NPIX/64, 256, 0, stream>>>(feat, feat_t);
    enc_kernel<<<528, 256, 0, stream>>>(feat, w1t, w2t, bns, bnsh, b1, b2, probs);
    geomhist_kernel<<<NPTS/256, 256, 0, stream>>>(ext, kinv, startp + 1);
    scanA_kernel<<<NSCANB, 256, 0, stream>>>(startp, cursor, bsum);
    scanB_kernel<<<1, 512, 0, stream>>>(bsum);
    scanC_kernel<<<NSCANB, 256, 0, stream>>>(startp, cursor, bsum);
    geomscatter_kernel<<<NPTS/256, 256, 0, stream>>>(ext, kinv, probs, cursor, plist2);
    gather2_kernel<<<NTILE, 1024, 0, stream>>>(feat_t, startp, plist2, out);
}

// Round 11
// 313.664 us; speedup vs baseline: 8.1562x; 1.4891x over previous
//
#include <hip/hip_runtime.h>
#include <math.h>

#define B_   2
#define N_   6
#define C_   64
#define D_   64
#define FH_  16
#define FW_  44
#define BN_  (B_*N_)              // 12
#define PIX_ (FH_*FW_)            // 704
#define NPIX (BN_*PIX_)           // 8448
#define NPTS (BN_*D_*PIX_)        // 540672
#define PPBN (D_*PIX_)            // 45056 points per (b,n) image
#define BEVH 200
#define BEVW 200
#define NCELL (BEVH*BEVW)         // 40000
#define NBCELL (B_*NCELL)         // 80000
#define NSCANB ((NBCELL + 255)/256)  // 313 scan blocks
#define PPW  128                  // points per wave in gather3
#define GBLK ((NPTS + PPW*4 - 1)/(PPW*4))  // 1056 gather blocks (4 waves)
// record pack: pixg (14 bits, max 8447) | fc << 14 (17 bits, max 79999)
// max value 79999*2^14 + 16383 < 2^31 -> non-negative int32.  [r10 bug: was 13]

// ---------------- zero helpers ----------------
__global__ void zero_i_kernel(int* __restrict__ p, int n) {
    int i = blockIdx.x * blockDim.x + threadIdx.x;
    if (i < n) p[i] = 0;
}
__global__ void zero_f4_kernel(float4* __restrict__ p, int n4) {
    int i = blockIdx.x * blockDim.x + threadIdx.x;
    if (i < n4) p[i] = float4{0.f, 0.f, 0.f, 0.f};
}

// ---------------- weight transposes (parallel) ----------------
__global__ __launch_bounds__(256) void transW_kernel(
        const float* __restrict__ w1, const float* __restrict__ w2,
        float* __restrict__ w1t, float* __restrict__ w2t) {
    int idx = blockIdx.x * 256 + threadIdx.x;
    if (idx < C_*C_*9) {
        int cout = idx / (C_*9);
        int r    = idx % (C_*9);
        w1t[r*C_ + cout] = w1[idx];
    } else if (idx < C_*C_*9 + D_*C_) {
        int j = idx - C_*C_*9;
        int d = j / C_, c = j % C_;
        w2t[c*D_ + d] = w2[j];
    }
}

// ---------------- small prep: BN affine + LAPACK-f32 Kinv ----------------
__global__ __launch_bounds__(64) void prep_small_kernel(
        const float* __restrict__ gamma, const float* __restrict__ beta,
        const float* __restrict__ rmean, const float* __restrict__ rvar,
        const float* __restrict__ intr,
        float* __restrict__ bns, float* __restrict__ bnsh,
        float* __restrict__ kinv) {
#pragma clang fp contract(off)
    int t = threadIdx.x;
    if (t < C_) {
        float s = gamma[t] / sqrtf(rvar[t] + 1e-5f);
        bns[t]  = s;
        bnsh[t] = beta[t] - rmean[t] * s;
    }
    if (t < BN_) {
        const float* K = intr + t*9;
        float A[3][3];
        for (int r = 0; r < 3; r++)
            for (int cc = 0; cc < 3; cc++) A[r][cc] = K[r*3 + cc];
        int ipiv[3];
        for (int j = 0; j < 3; j++) {
            int p = j; float mx = fabsf(A[j][j]);
            for (int i = j+1; i < 3; i++) {
                float v = fabsf(A[i][j]);
                if (v > mx) { mx = v; p = i; }
            }
            ipiv[j] = p;
            if (p != j)
                for (int k = 0; k < 3; k++) { float tm = A[j][k]; A[j][k] = A[p][k]; A[p][k] = tm; }
            float rpiv = 1.0f / A[j][j];
            for (int i = j+1; i < 3; i++) A[i][j] = A[i][j] * rpiv;
            for (int k = j+1; k < 3; k++)
                for (int i = j+1; i < 3; i++)
                    A[i][k] = A[i][k] - A[i][j] * A[j][k];
        }
        for (int j = 0; j < 3; j++) {
            float ajj = 1.0f / A[j][j];
            A[j][j] = ajj;
            float najj = -ajj;
            for (int jj = 0; jj < j; jj++) {
                float temp = A[jj][j];
                for (int i = 0; i < jj; i++) A[i][j] = A[i][j] + temp * A[i][jj];
                A[jj][j] = A[jj][j] * A[jj][jj];
            }
            for (int i = 0; i < j; i++) A[i][j] = A[i][j] * najj;
        }
        for (int j = 1; j >= 0; j--) {
            float work[3];
            for (int i = j+1; i < 3; i++) { work[i] = A[i][j]; A[i][j] = 0.0f; }
            for (int k = j+1; k < 3; k++)
                for (int i = 0; i < 3; i++)
                    A[i][j] = A[i][j] - A[i][k] * work[k];
        }
        for (int j = 2; j >= 0; j--) {
            int p = ipiv[j];
            if (p != j)
                for (int i = 0; i < 3; i++) { float tm = A[i][j]; A[i][j] = A[i][p]; A[i][p] = tm; }
        }
        for (int k = 0; k < 9; k++) kinv[t*9 + k] = A[k/3][k%3];
    }
}

// ---------------- feat transpose: [bn][c][pix] -> [bn*704+pix][c] ----------------
__global__ __launch_bounds__(256) void featT_kernel(
        const float* __restrict__ feat, float* __restrict__ feat_t) {
    __shared__ float lds[64][65];
    int j    = blockIdx.x;
    int bn   = j / 11;
    int pb   = (j % 11) * 64;
    int t    = threadIdx.x;
    int lane = t & 63;
    int r0   = t >> 6;
#pragma unroll
    for (int rr = 0; rr < 16; rr++) {
        int c = r0 + 4*rr;
        lds[c][lane] = feat[((size_t)bn*C_ + c)*PIX_ + pb + lane];
    }
    __syncthreads();
#pragma unroll
    for (int rr = 0; rr < 16; rr++) {
        int pr = r0 + 4*rr;
        feat_t[((size_t)bn*PIX_ + pb + pr)*C_ + lane] = lds[lane][pr];
    }
}

// ---------------- enc: LDS-staged weights, 4 pixels/wave -----------------
__global__ __launch_bounds__(256) void enc_kernel(
        const float* __restrict__ feat,
        const float* __restrict__ w1t, const float* __restrict__ w2t,
        const float* __restrict__ bns, const float* __restrict__ bnsh,
        const float* __restrict__ b1,  const float* __restrict__ b2,
        float* __restrict__ probs) {
    __shared__ float wlds[16*9*C_];    // 36 KB
    __shared__ float hl[16][C_];       // 4 KB
    int blk = blockIdx.x;              // 0..527
    int bn  = blk / 44;
    int rem = blk % 44;
    int yt  = rem / 11;
    int xt  = rem % 11;
    int t   = threadIdx.x;
    int c   = t & 63;
    int w   = __builtin_amdgcn_readfirstlane(t >> 6);
    int y   = yt*4 + w;
    int x0  = xt*4;

    float h0 = b1[c], h1 = h0, h2 = h0, h3 = h0;
    const float* fbn = feat + (size_t)bn * C_ * PIX_;

    for (int cc = 0; cc < C_; cc += 16) {
        __syncthreads();
        {
            const float4* s4 = (const float4*)(w1t + cc*9*C_);
            float4* d4 = (float4*)wlds;
#pragma unroll
            for (int i = 0; i < 9; i++)
                d4[t + 256*i] = s4[t + 256*i];
        }
        __syncthreads();
        for (int ci = 0; ci < 16; ci++) {
            const float* fc = fbn + (cc + ci) * PIX_;
            const float* wl = wlds + ci*9*C_;
#pragma unroll
            for (int ky = 0; ky < 3; ky++) {
                int iy2 = y + ky - 1;
                if (iy2 < 0 || iy2 >= FH_) continue;
                const float* frow = fc + iy2 * FW_;
#pragma unroll
                for (int kx = 0; kx < 3; kx++) {
                    float wv = wl[(ky*3 + kx)*C_ + c];
                    int xs = x0 + kx - 1;
                    if (xs >= 0)       h0 = fmaf(wv, frow[xs],     h0);
                    h1 = fmaf(wv, frow[xs + 1], h1);
                    h2 = fmaf(wv, frow[xs + 2], h2);
                    if (xs + 3 < FW_)  h3 = fmaf(wv, frow[xs + 3], h3);
                }
            }
        }
    }

    float sc = bns[c], sh = bnsh[c];
    {
        float v0 = fmaf(h0, sc, sh); hl[w*4 + 0][c] = v0 > 0.f ? v0 : 0.f;
        float v1 = fmaf(h1, sc, sh); hl[w*4 + 1][c] = v1 > 0.f ? v1 : 0.f;
        float v2 = fmaf(h2, sc, sh); hl[w*4 + 2][c] = v2 > 0.f ? v2 : 0.f;
        float v3 = fmaf(h3, sc, sh); hl[w*4 + 3][c] = v3 > 0.f ? v3 : 0.f;
    }
    __syncthreads();

    float l0 = b2[c], l1 = l0, l2 = l0, l3 = l0;
    for (int c2 = 0; c2 < C_; c2++) {
        float wv = w2t[c2*D_ + c];
        l0 = fmaf(wv, hl[w*4 + 0][c2], l0);
        l1 = fmaf(wv, hl[w*4 + 1][c2], l1);
        l2 = fmaf(wv, hl[w*4 + 2][c2], l2);
        l3 = fmaf(wv, hl[w*4 + 3][c2], l3);
    }

    float lv[4] = {l0, l1, l2, l3};
#pragma unroll
    for (int p = 0; p < 4; p++) {
        float l = lv[p];
        float m = l;
        for (int off = 32; off; off >>= 1) m = fmaxf(m, __shfl_xor(m, off));
        float e = expf(l - m);
        float s = e;
        for (int off = 32; off; off >>= 1) s += __shfl_xor(s, off);
        probs[((size_t)bn*PIX_ + y*FW_ + x0 + p)*D_ + c] = e / s;
    }
}

// ---------------- geometry: cell for point i (f32 chain, validated r4) ------
__device__ __forceinline__ int compute_cell(int i, const float* __restrict__ kinv,
                                            const float* __restrict__ ext) {
#pragma clang fp contract(off)
    int x  = i % FW_;
    int y  = (i / FW_) % FH_;
    int d  = (i / PIX_) % D_;
    int bn = i / PPBN;

    const float* kv = kinv + bn*9;
    const float* e  = ext  + bn*16;

    float u  = (x == FW_-1) ? 703.0f : (float)((double)x * (703.0/43.0));
    float vv = (float)((double)y * 17.0);
    float dd = (d == D_-1) ? 60.0f  : (float)(1.0 + (double)d * (59.0/63.0));

    float px = u * dd;
    float py = vv * dd;
    float pz = dd;

    float cx = (kv[0]*px + kv[1]*py) + kv[2]*pz;
    float cy = (kv[3]*px + kv[4]*py) + kv[5]*pz;
    float cz = (kv[6]*px + kv[7]*py) + kv[8]*pz;

    float ex = (e[0]*cx + e[1]*cy) + e[2]*cz;
    float ey = (e[4]*cx + e[5]*cy) + e[6]*cz;
    ex = ex + e[3];
    ey = ey + e[7];

    float gx = (ex + 50.0f) / 0.5f;
    float gy = (ey + 50.0f) / 0.5f;
    int ix = (int)floorf(gx);
    int iy = (int)floorf(gy);
    return (ix >= 0 && ix < BEVW && iy >= 0 && iy < BEVH) ? (iy*BEVW + ix) : -1;
}

// ---- wave run-aggregation helpers (consecutive i share cells at small d) ----
__device__ __forceinline__ void run_info(int fc, int lane,
                                         bool& isLeader, int& runLen, int& lead) {
    int prev = __shfl_up(fc, 1);
    isLeader = (lane == 0) || (fc != prev);
    unsigned long long mask = __ballot(isLeader);
    unsigned long long hi = (lane == 63) ? 0ull : (mask >> (lane + 1));
    int next = hi ? (lane + 1 + __builtin_ctzll(hi)) : 64;
    runLen = next - lane;
    unsigned long long lo = mask & (~0ull >> (63 - lane));
    lead = 63 - __builtin_clzll(lo);
}

// ---------------- geom + histogram (wave-aggregated) ----------------
__global__ __launch_bounds__(256) void geomhist_kernel(
        const float* __restrict__ ext, const float* __restrict__ kinv,
        int* __restrict__ counts) {
    int i = blockIdx.x * 256 + threadIdx.x;
    int lane = threadIdx.x & 63;
    int fc = -1;
    if (i < NPTS) {
        int cell = compute_cell(i, kinv, ext);
        if (cell >= 0) fc = (i / (PPBN * N_)) * NCELL + cell;
    }
    bool isLeader; int runLen, lead;
    run_info(fc, lane, isLeader, runLen, lead);
    if (isLeader && fc >= 0) atomicAdd(&counts[fc], runLen);
}

// ---------------- 3-phase parallel scan over NBCELL counters ----------------
__global__ __launch_bounds__(256) void scanA_kernel(
        int* __restrict__ startp, int* __restrict__ cursor, int* __restrict__ bsum) {
    __shared__ int sdata[256];
    int t = threadIdx.x;
    int i = blockIdx.x * 256 + t;
    int v = (i < NBCELL) ? startp[1 + i] : 0;
    sdata[t] = v;
    __syncthreads();
#pragma unroll
    for (int off = 1; off < 256; off <<= 1) {
        int add = (t >= off) ? sdata[t - off] : 0;
        __syncthreads();
        sdata[t] += add;
        __syncthreads();
    }
    if (i < NBCELL) {
        startp[1 + i] = sdata[t];
        cursor[i]     = sdata[t] - v;
    }
    if (t == 255) bsum[blockIdx.x] = sdata[255];
}

__global__ __launch_bounds__(512) void scanB_kernel(int* __restrict__ bsum) {
    __shared__ int sdata[512];
    int t = threadIdx.x;
    int v = (t < NSCANB) ? bsum[t] : 0;
    sdata[t] = v;
    __syncthreads();
#pragma unroll
    for (int off = 1; off < 512; off <<= 1) {
        int add = (t >= off) ? sdata[t - off] : 0;
        __syncthreads();
        sdata[t] += add;
        __syncthreads();
    }
    if (t < NSCANB) bsum[t] = sdata[t] - v;
}

__global__ __launch_bounds__(256) void scanC_kernel(
        int* __restrict__ startp, int* __restrict__ cursor,
        const int* __restrict__ bsum) {
    int blk = blockIdx.x;
    int t   = threadIdx.x;
    int i   = blk * 256 + t;
    if (i >= NBCELL) return;
    int off = bsum[blk];
    startp[1 + i] += off;
    cursor[i]     += off;
}

// ---------------- geom + scatter packed records (wave-aggregated) -----------
// record: .x = prob bits, .y = pixg | (fc << 14)
__global__ __launch_bounds__(256) void geomscatter_kernel(
        const float* __restrict__ ext, const float* __restrict__ kinv,
        const float* __restrict__ probs,
        int* __restrict__ cursor, int2* __restrict__ plist2) {
    int i = blockIdx.x * 256 + threadIdx.x;
    int lane = threadIdx.x & 63;
    int fc = -1, pixg = 0;
    float pr = 0.f;
    if (i < NPTS) {
        int cell = compute_cell(i, kinv, ext);
        if (cell >= 0) {
            int pix = i % PIX_;
            int d   = (i / PIX_) % D_;
            int bn  = i / PPBN;
            fc   = (bn / N_) * NCELL + cell;
            pixg = bn*PIX_ + pix;
            pr   = probs[(size_t)pixg*D_ + d];
        }
    }
    bool isLeader; int runLen, lead;
    run_info(fc, lane, isLeader, runLen, lead);
    int base = 0;
    if (isLeader && fc >= 0) base = atomicAdd(&cursor[fc], runLen);
    base = __shfl(base, lead);
    if (fc >= 0)
        plist2[base + (lane - lead)] = make_int2(__float_as_int(pr),
                                                 pixg | (fc << 14));
}

// ---------------- gather3: point-balanced, ownership-based ------------------
// wave W covers plist[W*PPW, (W+1)*PPW) snapped to cell boundaries.
// small cell (len<=2*PPW): owned by the wave containing its START -> plain
// store. big cell: each overlapping wave adds its slice via atomicAdd.
__global__ __launch_bounds__(256) void gather3_kernel(
        const float* __restrict__ feat_t, const int* __restrict__ startp,
        const int2* __restrict__ plist2, float* __restrict__ out) {
    int gid  = blockIdx.x * 256 + threadIdx.x;
    int W    = gid >> 6;
    int lane = gid & 63;
    int total = startp[NBCELL];
    int p0 = W * PPW;
    if (p0 >= total) return;
    int pe = min(p0 + PPW, total);
    int p  = p0;

    // head: cell continuing from a previous wave's range
    {
        int2 r = plist2[p0];
        int fc = ((unsigned)r.y) >> 14;
        int cs = startp[fc], ce = startp[fc + 1];
        if (cs < p0) {
            if (ce - cs > 2*PPW) {        // big: process our slice
                int b2 = min(pe, ce);
                float acc = 0.f;
                for (int q = p0; q < b2; q++) {
                    int2 rr = plist2[q];
                    acc = fmaf(__int_as_float(rr.x),
                               feat_t[(size_t)(rr.y & 0x3FFF)*C_ + lane], acc);
                }
                int bb   = fc >= NCELL;
                int cell = fc - bb*NCELL;
                atomicAdd(out + ((size_t)(bb*C_ + lane))*NCELL + cell, acc);
            }
            p = ce;                        // small: skip (owned upstream)
        }
    }
    // cells starting in [p, pe)
    while (p < pe) {
        int2 r = plist2[p];
        int fc = ((unsigned)r.y) >> 14;
        int ce = startp[fc + 1];
        int len = ce - p;                  // p == cell start here
        bool big = (len > 2*PPW);
        int b2 = big ? min(ce, pe) : ce;   // small may extend past pe (owned)
        float acc = 0.f;
        for (int q = p; q < b2; q++) {
            int2 rr = plist2[q];
            acc = fmaf(__int_as_float(rr.x),
                       feat_t[(size_t)(rr.y & 0x3FFF)*C_ + lane], acc);
        }
        int bb   = fc >= NCELL;
        int cell = fc - bb*NCELL;
        float* addr = out + ((size_t)(bb*C_ + lane))*NCELL + cell;
        if (big) atomicAdd(addr, acc);
        else     *addr = acc;
        p = ce;
    }
}

extern "C" void kernel_launch(void* const* d_in, const int* in_sizes, int n_in,
                              void* d_out, int out_size, void* d_ws, size_t ws_size,
                              hipStream_t stream) {
    const float* feat  = (const float*)d_in[0];
    const float* intr  = (const float*)d_in[1];
    const float* ext   = (const float*)d_in[2];
    const float* w1    = (const float*)d_in[3];
    const float* b1    = (const float*)d_in[4];
    const float* gamma = (const float*)d_in[5];
    const float* beta  = (const float*)d_in[6];
    const float* rmean = (const float*)d_in[7];
    const float* rvar  = (const float*)d_in[8];
    const float* w2    = (const float*)d_in[9];
    const float* b2    = (const float*)d_in[10];
    float* out = (float*)d_out;
    (void)in_sizes; (void)n_in; (void)ws_size;

    // workspace layout (plist2 first for 8B alignment); total ~9.5 MB
    int2*  plist2 = (int2*)d_ws;                    // NPTS int2 = 4.33 MB
    float* w1t    = (float*)(plist2 + NPTS);        // 36864
    float* w2t    = w1t + C_*C_*9;                  // 4096
    float* bns    = w2t + D_*C_;                    // 64
    float* bnsh   = bns + C_;                       // 64
    float* kinv   = bnsh + C_;                      // 108
    float* probs  = kinv + BN_*9;                   // 540672
    float* feat_t = probs + NPTS;                   // 540672
    int*   startp = (int*)(feat_t + NPTS);          // 80001
    int*   cursor = startp + (NBCELL + 1);          // 80000
    int*   bsum   = cursor + NBCELL;                // 313

    // ---- pipeline ----
    zero_i_kernel<<<(NBCELL + 256)/256, 256, 0, stream>>>(startp, NBCELL + 1);
    zero_f4_kernel<<<(out_size/4 + 255)/256, 256, 0, stream>>>((float4*)out, out_size/4);
    transW_kernel<<<(C_*C_*9 + D_*C_ + 255)/256, 256, 0, stream>>>(w1, w2, w1t, w2t);
    prep_small_kernel<<<1, 64, 0, stream>>>(gamma, beta, rmean, rvar, intr,
                                            bns, bnsh, kinv);
    featT_kernel<<<NPIX/64, 256, 0, stream>>>(feat, feat_t);
    enc_kernel<<<528, 256, 0, stream>>>(feat, w1t, w2t, bns, bnsh, b1, b2, probs);
    geomhist_kernel<<<NPTS/256, 256, 0, stream>>>(ext, kinv, startp + 1);
    scanA_kernel<<<NSCANB, 256, 0, stream>>>(startp, cursor, bsum);
    scanB_kernel<<<1, 512, 0, stream>>>(bsum);
    scanC_kernel<<<NSCANB, 256, 0, stream>>>(startp, cursor, bsum);
    geomscatter_kernel<<<NPTS/256, 256, 0, stream>>>(ext, kinv, probs, cursor, plist2);
    gather3_kernel<<<GBLK, 256, 0, stream>>>(feat_t, startp, plist2, out);
}

// Round 12
// 274.633 us; speedup vs baseline: 9.3154x; 1.1421x over previous
//
#include <hip/hip_runtime.h>
#include <math.h>

#define B_   2
#define N_   6
#define C_   64
#define D_   64
#define FH_  16
#define FW_  44
#define BN_  (B_*N_)              // 12
#define PIX_ (FH_*FW_)            // 704
#define NPIX (BN_*PIX_)           // 8448
#define NPTS (BN_*D_*PIX_)        // 540672
#define PPBN (D_*PIX_)            // 45056 points per (b,n) image
#define BEVH 200
#define BEVW 200
#define NCELL (BEVH*BEVW)         // 40000
#define NBCELL (B_*NCELL)         // 80000
#define NSCANB ((NBCELL + 255)/256)  // 313 scan blocks
#define PPW  64                   // points per wave in gather3 (r11: 128)
#define GBLK (NPTS/(PPW*4))       // 2112 gather blocks (4 waves each)
// record pack: pixg (14 bits, max 8447) | fc << 14 (17 bits, max 79999) -> <2^31

// setup mega-kernel block ranges
#define NB_ZOUT 5000              // out zero: 5.12M f32 = 1.28M float4
#define NB_ZSP  313               // startp zero (80001 ints)
#define NB_TW   160               // weight transposes (40960 elems)
#define NB_PREP 1                 // BN affine + Kinv
#define NB_FT   132               // feat transpose
#define NB_SETUP (NB_ZOUT + NB_ZSP + NB_TW + NB_PREP + NB_FT)   // 5606

// ---------------- setup: zero out + zero startp + transW + prep + featT -----
__global__ __launch_bounds__(256) void setup_kernel(
        const float* __restrict__ feat, const float* __restrict__ w1,
        const float* __restrict__ w2,
        const float* __restrict__ gamma, const float* __restrict__ beta,
        const float* __restrict__ rmean, const float* __restrict__ rvar,
        const float* __restrict__ intr,
        float* __restrict__ out, int* __restrict__ startp,
        float* __restrict__ w1t, float* __restrict__ w2t,
        float* __restrict__ bns, float* __restrict__ bnsh,
        float* __restrict__ kinv, float* __restrict__ feat_t) {
#pragma clang fp contract(off)
    __shared__ float lds[64][65];
    int blk = blockIdx.x;
    int t   = threadIdx.x;

    if (blk < NB_ZOUT) {
        ((float4*)out)[blk*256 + t] = float4{0.f, 0.f, 0.f, 0.f};
        return;
    }
    blk -= NB_ZOUT;
    if (blk < NB_ZSP) {
        int i = blk*256 + t;
        if (i < NBCELL + 1) startp[i] = 0;
        return;
    }
    blk -= NB_ZSP;
    if (blk < NB_TW) {
        int idx = blk*256 + t;
        if (idx < C_*C_*9) {
            int cout = idx / (C_*9);
            int r    = idx % (C_*9);
            w1t[r*C_ + cout] = w1[idx];
        } else if (idx < C_*C_*9 + D_*C_) {
            int j = idx - C_*C_*9;
            int d = j / C_, c = j % C_;
            w2t[c*D_ + d] = w2[j];
        }
        return;
    }
    blk -= NB_TW;
    if (blk < NB_PREP) {
        if (t < C_) {
            float s = gamma[t] / sqrtf(rvar[t] + 1e-5f);
            bns[t]  = s;
            bnsh[t] = beta[t] - rmean[t] * s;
        }
        if (t < BN_) {
            const float* K = intr + t*9;
            float A[3][3];
            for (int r = 0; r < 3; r++)
                for (int cc = 0; cc < 3; cc++) A[r][cc] = K[r*3 + cc];
            int ipiv[3];
            // sgetf2
            for (int j = 0; j < 3; j++) {
                int p = j; float mx = fabsf(A[j][j]);
                for (int i = j+1; i < 3; i++) {
                    float v = fabsf(A[i][j]);
                    if (v > mx) { mx = v; p = i; }
                }
                ipiv[j] = p;
                if (p != j)
                    for (int k = 0; k < 3; k++) { float tm = A[j][k]; A[j][k] = A[p][k]; A[p][k] = tm; }
                float rpiv = 1.0f / A[j][j];
                for (int i = j+1; i < 3; i++) A[i][j] = A[i][j] * rpiv;
                for (int k = j+1; k < 3; k++)
                    for (int i = j+1; i < 3; i++)
                        A[i][k] = A[i][k] - A[i][j] * A[j][k];
            }
            // strti2
            for (int j = 0; j < 3; j++) {
                float ajj = 1.0f / A[j][j];
                A[j][j] = ajj;
                float najj = -ajj;
                for (int jj = 0; jj < j; jj++) {
                    float temp = A[jj][j];
                    for (int i = 0; i < jj; i++) A[i][j] = A[i][j] + temp * A[i][jj];
                    A[jj][j] = A[jj][j] * A[jj][jj];
                }
                for (int i = 0; i < j; i++) A[i][j] = A[i][j] * najj;
            }
            // sgetri
            for (int j = 1; j >= 0; j--) {
                float work[3];
                for (int i = j+1; i < 3; i++) { work[i] = A[i][j]; A[i][j] = 0.0f; }
                for (int k = j+1; k < 3; k++)
                    for (int i = 0; i < 3; i++)
                        A[i][j] = A[i][j] - A[i][k] * work[k];
            }
            for (int j = 2; j >= 0; j--) {
                int p = ipiv[j];
                if (p != j)
                    for (int i = 0; i < 3; i++) { float tm = A[i][j]; A[i][j] = A[i][p]; A[i][p] = tm; }
            }
            for (int k = 0; k < 9; k++) kinv[t*9 + k] = A[k/3][k%3];
        }
        return;
    }
    blk -= NB_PREP;
    // featT: [bn][c][pix] -> [bn*704+pix][c]
    {
        int bn   = blk / 11;
        int pb   = (blk % 11) * 64;
        int lane = t & 63;
        int r0   = t >> 6;
#pragma unroll
        for (int rr = 0; rr < 16; rr++) {
            int c = r0 + 4*rr;
            lds[c][lane] = feat[((size_t)bn*C_ + c)*PIX_ + pb + lane];
        }
        __syncthreads();
#pragma unroll
        for (int rr = 0; rr < 16; rr++) {
            int pr = r0 + 4*rr;
            feat_t[((size_t)bn*PIX_ + pb + pr)*C_ + lane] = lds[lane][pr];
        }
    }
}

// ---------------- enc: LDS-staged weights, 4 pixels/wave -----------------
__global__ __launch_bounds__(256) void enc_kernel(
        const float* __restrict__ feat,
        const float* __restrict__ w1t, const float* __restrict__ w2t,
        const float* __restrict__ bns, const float* __restrict__ bnsh,
        const float* __restrict__ b1,  const float* __restrict__ b2,
        float* __restrict__ probs) {
    __shared__ float wlds[16*9*C_];    // 36 KB
    __shared__ float hl[16][C_];       // 4 KB
    int blk = blockIdx.x;              // 0..527
    int bn  = blk / 44;
    int rem = blk % 44;
    int yt  = rem / 11;
    int xt  = rem % 11;
    int t   = threadIdx.x;
    int c   = t & 63;
    int w   = __builtin_amdgcn_readfirstlane(t >> 6);
    int y   = yt*4 + w;
    int x0  = xt*4;

    float h0 = b1[c], h1 = h0, h2 = h0, h3 = h0;
    const float* fbn = feat + (size_t)bn * C_ * PIX_;

    for (int cc = 0; cc < C_; cc += 16) {
        __syncthreads();
        {
            const float4* s4 = (const float4*)(w1t + cc*9*C_);
            float4* d4 = (float4*)wlds;
#pragma unroll
            for (int i = 0; i < 9; i++)
                d4[t + 256*i] = s4[t + 256*i];
        }
        __syncthreads();
        for (int ci = 0; ci < 16; ci++) {
            const float* fc = fbn + (cc + ci) * PIX_;
            const float* wl = wlds + ci*9*C_;
#pragma unroll
            for (int ky = 0; ky < 3; ky++) {
                int iy2 = y + ky - 1;
                if (iy2 < 0 || iy2 >= FH_) continue;
                const float* frow = fc + iy2 * FW_;
#pragma unroll
                for (int kx = 0; kx < 3; kx++) {
                    float wv = wl[(ky*3 + kx)*C_ + c];
                    int xs = x0 + kx - 1;
                    if (xs >= 0)       h0 = fmaf(wv, frow[xs],     h0);
                    h1 = fmaf(wv, frow[xs + 1], h1);
                    h2 = fmaf(wv, frow[xs + 2], h2);
                    if (xs + 3 < FW_)  h3 = fmaf(wv, frow[xs + 3], h3);
                }
            }
        }
    }

    float sc = bns[c], sh = bnsh[c];
    {
        float v0 = fmaf(h0, sc, sh); hl[w*4 + 0][c] = v0 > 0.f ? v0 : 0.f;
        float v1 = fmaf(h1, sc, sh); hl[w*4 + 1][c] = v1 > 0.f ? v1 : 0.f;
        float v2 = fmaf(h2, sc, sh); hl[w*4 + 2][c] = v2 > 0.f ? v2 : 0.f;
        float v3 = fmaf(h3, sc, sh); hl[w*4 + 3][c] = v3 > 0.f ? v3 : 0.f;
    }
    __syncthreads();

    float l0 = b2[c], l1 = l0, l2 = l0, l3 = l0;
    for (int c2 = 0; c2 < C_; c2++) {
        float wv = w2t[c2*D_ + c];
        l0 = fmaf(wv, hl[w*4 + 0][c2], l0);
        l1 = fmaf(wv, hl[w*4 + 1][c2], l1);
        l2 = fmaf(wv, hl[w*4 + 2][c2], l2);
        l3 = fmaf(wv, hl[w*4 + 3][c2], l3);
    }

    float lv[4] = {l0, l1, l2, l3};
#pragma unroll
    for (int p = 0; p < 4; p++) {
        float l = lv[p];
        float m = l;
        for (int off = 32; off; off >>= 1) m = fmaxf(m, __shfl_xor(m, off));
        float e = expf(l - m);
        float s = e;
        for (int off = 32; off; off >>= 1) s += __shfl_xor(s, off);
        probs[((size_t)bn*PIX_ + y*FW_ + x0 + p)*D_ + c] = e / s;
    }
}

// ---------------- geometry: cell for point i (f32 chain, validated r4) ------
__device__ __forceinline__ int compute_cell(int i, const float* __restrict__ kinv,
                                            const float* __restrict__ ext) {
#pragma clang fp contract(off)
    int x  = i % FW_;
    int y  = (i / FW_) % FH_;
    int d  = (i / PIX_) % D_;
    int bn = i / PPBN;

    const float* kv = kinv + bn*9;
    const float* e  = ext  + bn*16;

    float u  = (x == FW_-1) ? 703.0f : (float)((double)x * (703.0/43.0));
    float vv = (float)((double)y * 17.0);
    float dd = (d == D_-1) ? 60.0f  : (float)(1.0 + (double)d * (59.0/63.0));

    float px = u * dd;
    float py = vv * dd;
    float pz = dd;

    float cx = (kv[0]*px + kv[1]*py) + kv[2]*pz;
    float cy = (kv[3]*px + kv[4]*py) + kv[5]*pz;
    float cz = (kv[6]*px + kv[7]*py) + kv[8]*pz;

    float ex = (e[0]*cx + e[1]*cy) + e[2]*cz;
    float ey = (e[4]*cx + e[5]*cy) + e[6]*cz;
    ex = ex + e[3];
    ey = ey + e[7];

    float gx = (ex + 50.0f) / 0.5f;
    float gy = (ey + 50.0f) / 0.5f;
    int ix = (int)floorf(gx);
    int iy = (int)floorf(gy);
    return (ix >= 0 && ix < BEVW && iy >= 0 && iy < BEVH) ? (iy*BEVW + ix) : -1;
}

// ---- wave run-aggregation helpers ----
__device__ __forceinline__ void run_info(int fc, int lane,
                                         bool& isLeader, int& runLen, int& lead) {
    int prev = __shfl_up(fc, 1);
    isLeader = (lane == 0) || (fc != prev);
    unsigned long long mask = __ballot(isLeader);
    unsigned long long hi = (lane == 63) ? 0ull : (mask >> (lane + 1));
    int next = hi ? (lane + 1 + __builtin_ctzll(hi)) : 64;
    runLen = next - lane;
    unsigned long long lo = mask & (~0ull >> (63 - lane));
    lead = 63 - __builtin_clzll(lo);
}

// ---------------- geom + histogram (wave-aggregated) ----------------
__global__ __launch_bounds__(256) void geomhist_kernel(
        const float* __restrict__ ext, const float* __restrict__ kinv,
        int* __restrict__ counts) {
    int i = blockIdx.x * 256 + threadIdx.x;
    int lane = threadIdx.x & 63;
    int fc = -1;
    if (i < NPTS) {
        int cell = compute_cell(i, kinv, ext);
        if (cell >= 0) fc = (i / (PPBN * N_)) * NCELL + cell;
    }
    bool isLeader; int runLen, lead;
    run_info(fc, lane, isLeader, runLen, lead);
    if (isLeader && fc >= 0) atomicAdd(&counts[fc], runLen);
}

// ---------------- scanA: block-local scan ----------------
__global__ __launch_bounds__(256) void scanA_kernel(
        int* __restrict__ startp, int* __restrict__ cursor, int* __restrict__ bsum) {
    __shared__ int sdata[256];
    int t = threadIdx.x;
    int i = blockIdx.x * 256 + t;
    int v = (i < NBCELL) ? startp[1 + i] : 0;
    sdata[t] = v;
    __syncthreads();
#pragma unroll
    for (int off = 1; off < 256; off <<= 1) {
        int add = (t >= off) ? sdata[t - off] : 0;
        __syncthreads();
        sdata[t] += add;
        __syncthreads();
    }
    if (i < NBCELL) {
        startp[1 + i] = sdata[t];
        cursor[i]     = sdata[t] - v;
    }
    if (t == 255) bsum[blockIdx.x] = sdata[255];
}

// ---------------- scanC': re-scan bsum in LDS + apply offsets ---------------
// 157 blocks x 512 threads; block covers 512 cells.
__global__ __launch_bounds__(512) void scanC_kernel(
        int* __restrict__ startp, int* __restrict__ cursor,
        const int* __restrict__ bsum) {
    __shared__ int sdata[512];
    int t = threadIdx.x;
    int v = (t < NSCANB) ? bsum[t] : 0;
    sdata[t] = v;
    __syncthreads();
#pragma unroll
    for (int off = 1; off < 512; off <<= 1) {
        int add = (t >= off) ? sdata[t - off] : 0;
        __syncthreads();
        sdata[t] += add;
        __syncthreads();
    }
    int i = blockIdx.x * 512 + t;
    if (i >= NBCELL) return;
    int j = i >> 8;                       // which scanA block
    int off = (j == 0) ? 0 : sdata[j - 1];
    startp[1 + i] += off;
    cursor[i]     += off;
}

// ---------------- geom + scatter packed records (wave-aggregated) -----------
// record: .x = prob bits, .y = pixg | (fc << 14)
__global__ __launch_bounds__(256) void geomscatter_kernel(
        const float* __restrict__ ext, const float* __restrict__ kinv,
        const float* __restrict__ probs,
        int* __restrict__ cursor, int2* __restrict__ plist2) {
    int i = blockIdx.x * 256 + threadIdx.x;
    int lane = threadIdx.x & 63;
    int fc = -1, pixg = 0;
    float pr = 0.f;
    if (i < NPTS) {
        int cell = compute_cell(i, kinv, ext);
        if (cell >= 0) {
            int pix = i % PIX_;
            int d   = (i / PIX_) % D_;
            int bn  = i / PPBN;
            fc   = (bn / N_) * NCELL + cell;
            pixg = bn*PIX_ + pix;
            pr   = probs[(size_t)pixg*D_ + d];
        }
    }
    bool isLeader; int runLen, lead;
    run_info(fc, lane, isLeader, runLen, lead);
    int base = 0;
    if (isLeader && fc >= 0) base = atomicAdd(&cursor[fc], runLen);
    base = __shfl(base, lead);
    if (fc >= 0)
        plist2[base + (lane - lead)] = make_int2(__float_as_int(pr),
                                                 pixg | (fc << 14));
}

// ---------------- gather3: point-balanced, ownership-based ------------------
// wave W covers plist[W*PPW, (W+1)*PPW) snapped to cell boundaries.
// small cell (len<=2*PPW): owned by the wave containing its START -> store.
// big cell: each overlapping wave adds its slice via atomicAdd.
__global__ __launch_bounds__(256) void gather3_kernel(
        const float* __restrict__ feat_t, const int* __restrict__ startp,
        const int2* __restrict__ plist2, float* __restrict__ out) {
    int gid  = blockIdx.x * 256 + threadIdx.x;
    int W    = gid >> 6;
    int lane = gid & 63;
    int total = startp[NBCELL];
    int p0 = W * PPW;
    if (p0 >= total) return;
    int pe = min(p0 + PPW, total);
    int p  = p0;

    // head: cell continuing from a previous wave's range
    {
        int2 r = plist2[p0];
        int fc = ((unsigned)r.y) >> 14;
        int cs = startp[fc], ce = startp[fc + 1];
        if (cs < p0) {
            if (ce - cs > 2*PPW) {        // big: process our slice
                int b2 = min(pe, ce);
                float acc = 0.f;
                for (int q = p0; q < b2; q++) {
                    int2 rr = plist2[q];
                    acc = fmaf(__int_as_float(rr.x),
                               feat_t[(size_t)(rr.y & 0x3FFF)*C_ + lane], acc);
                }
                int bb   = fc >= NCELL;
                int cell = fc - bb*NCELL;
                atomicAdd(out + ((size_t)(bb*C_ + lane))*NCELL + cell, acc);
            }
            p = ce;                        // small: skip (owned upstream)
        }
    }
    // cells starting in [p, pe)
    while (p < pe) {
        int2 r = plist2[p];
        int fc = ((unsigned)r.y) >> 14;
        int ce = startp[fc + 1];
        int len = ce - p;                  // p == cell start here
        bool big = (len > 2*PPW);
        int b2 = big ? min(ce, pe) : ce;   // small may extend past pe (owned)
        float acc = 0.f;
        for (int q = p; q < b2; q++) {
            int2 rr = plist2[q];
            acc = fmaf(__int_as_float(rr.x),
                       feat_t[(size_t)(rr.y & 0x3FFF)*C_ + lane], acc);
        }
        int bb   = fc >= NCELL;
        int cell = fc - bb*NCELL;
        float* addr = out + ((size_t)(bb*C_ + lane))*NCELL + cell;
        if (big) atomicAdd(addr, acc);
        else     *addr = acc;
        p = ce;
    }
}

extern "C" void kernel_launch(void* const* d_in, const int* in_sizes, int n_in,
                              void* d_out, int out_size, void* d_ws, size_t ws_size,
                              hipStream_t stream) {
    const float* feat  = (const float*)d_in[0];
    const float* intr  = (const float*)d_in[1];
    const float* ext   = (const float*)d_in[2];
    const float* w1    = (const float*)d_in[3];
    const float* b1    = (const float*)d_in[4];
    const float* gamma = (const float*)d_in[5];
    const float* beta  = (const float*)d_in[6];
    const float* rmean = (const float*)d_in[7];
    const float* rvar  = (const float*)d_in[8];
    const float* w2    = (const float*)d_in[9];
    const float* b2    = (const float*)d_in[10];
    float* out = (float*)d_out;
    (void)in_sizes; (void)n_in; (void)out_size; (void)ws_size;

    // workspace layout (plist2 first for 8B alignment); total ~9.5 MB
    int2*  plist2 = (int2*)d_ws;                    // NPTS int2 = 4.33 MB
    float* w1t    = (float*)(plist2 + NPTS);        // 36864
    float* w2t    = w1t + C_*C_*9;                  // 4096
    float* bns    = w2t + D_*C_;                    // 64
    float* bnsh   = bns + C_;                       // 64
    float* kinv   = bnsh + C_;                      // 108
    float* probs  = kinv + BN_*9;                   // 540672
    float* feat_t = probs + NPTS;                   // 540672
    int*   startp = (int*)(feat_t + NPTS);          // 80001
    int*   cursor = startp + (NBCELL + 1);          // 80000
    int*   bsum   = cursor + NBCELL;                // 313

    // ---- 7-launch pipeline ----
    setup_kernel<<<NB_SETUP, 256, 0, stream>>>(feat, w1, w2, gamma, beta,
                                               rmean, rvar, intr, out, startp,
                                               w1t, w2t, bns, bnsh, kinv, feat_t);
    enc_kernel<<<528, 256, 0, stream>>>(feat, w1t, w2t, bns, bnsh, b1, b2, probs);
    geomhist_kernel<<<NPTS/256, 256, 0, stream>>>(ext, kinv, startp + 1);
    scanA_kernel<<<NSCANB, 256, 0, stream>>>(startp, cursor, bsum);
    scanC_kernel<<<(NBCELL + 511)/512, 512, 0, stream>>>(startp, cursor, bsum);
    geomscatter_kernel<<<NPTS/256, 256, 0, stream>>>(ext, kinv, probs, cursor, plist2);
    gather3_kernel<<<GBLK, 256, 0, stream>>>(feat_t, startp, plist2, out);
}

// Round 13
// 223.632 us; speedup vs baseline: 11.4399x; 1.2281x over previous
//
#include <hip/hip_runtime.h>
#include <math.h>

#define B_   2
#define N_   6
#define C_   64
#define D_   64
#define FH_  16
#define FW_  44
#define BN_  (B_*N_)              // 12
#define PIX_ (FH_*FW_)            // 704
#define NPIX (BN_*PIX_)           // 8448
#define NPTS (BN_*D_*PIX_)        // 540672
#define PPBN (D_*PIX_)            // 45056 points per (b,n) image
#define BEVH 200
#define BEVW 200
#define NCELL (BEVH*BEVW)         // 40000
#define NBCELL (B_*NCELL)         // 80000
#define NSCANB ((NBCELL + 255)/256)  // 313 scan blocks
#define PPW  64                   // points per wave in gather3
#define GBLK (NPTS/(PPW*4))       // 2112 gather blocks (4 waves each)
// record pack: pixg (14 bits, max 8447) | fc << 14 (17 bits, max 79999) -> <2^31

// setup mega-kernel block ranges
#define NB_ZOUT 5000              // out zero: 5.12M f32 = 1.28M float4
#define NB_ZSP  313               // startp zero (80001 ints)
#define NB_TW   160               // weight transposes (40960 elems)
#define NB_PREP 1                 // BN affine + Kinv
#define NB_FT   132               // feat transpose
#define NB_SETUP (NB_ZOUT + NB_ZSP + NB_TW + NB_PREP + NB_FT)   // 5606

// ---------------- setup: zero out + zero startp + transW + prep + featT -----
__global__ __launch_bounds__(256) void setup_kernel(
        const float* __restrict__ feat, const float* __restrict__ w1,
        const float* __restrict__ w2,
        const float* __restrict__ gamma, const float* __restrict__ beta,
        const float* __restrict__ rmean, const float* __restrict__ rvar,
        const float* __restrict__ intr,
        float* __restrict__ out, int* __restrict__ startp,
        float* __restrict__ w1t, float* __restrict__ w2t,
        float* __restrict__ bns, float* __restrict__ bnsh,
        float* __restrict__ kinv, float* __restrict__ feat_t) {
#pragma clang fp contract(off)
    __shared__ float lds[64][65];
    int blk = blockIdx.x;
    int t   = threadIdx.x;

    if (blk < NB_ZOUT) {
        ((float4*)out)[blk*256 + t] = float4{0.f, 0.f, 0.f, 0.f};
        return;
    }
    blk -= NB_ZOUT;
    if (blk < NB_ZSP) {
        int i = blk*256 + t;
        if (i < NBCELL + 1) startp[i] = 0;
        return;
    }
    blk -= NB_ZSP;
    if (blk < NB_TW) {
        int idx = blk*256 + t;
        if (idx < C_*C_*9) {
            int cout = idx / (C_*9);
            int r    = idx % (C_*9);
            w1t[r*C_ + cout] = w1[idx];
        } else if (idx < C_*C_*9 + D_*C_) {
            int j = idx - C_*C_*9;
            int d = j / C_, c = j % C_;
            w2t[c*D_ + d] = w2[j];
        }
        return;
    }
    blk -= NB_TW;
    if (blk < NB_PREP) {
        if (t < C_) {
            float s = gamma[t] / sqrtf(rvar[t] + 1e-5f);
            bns[t]  = s;
            bnsh[t] = beta[t] - rmean[t] * s;
        }
        if (t < BN_) {
            const float* K = intr + t*9;
            float A[3][3];
            for (int r = 0; r < 3; r++)
                for (int cc = 0; cc < 3; cc++) A[r][cc] = K[r*3 + cc];
            int ipiv[3];
            // sgetf2
            for (int j = 0; j < 3; j++) {
                int p = j; float mx = fabsf(A[j][j]);
                for (int i = j+1; i < 3; i++) {
                    float v = fabsf(A[i][j]);
                    if (v > mx) { mx = v; p = i; }
                }
                ipiv[j] = p;
                if (p != j)
                    for (int k = 0; k < 3; k++) { float tm = A[j][k]; A[j][k] = A[p][k]; A[p][k] = tm; }
                float rpiv = 1.0f / A[j][j];
                for (int i = j+1; i < 3; i++) A[i][j] = A[i][j] * rpiv;
                for (int k = j+1; k < 3; k++)
                    for (int i = j+1; i < 3; i++)
                        A[i][k] = A[i][k] - A[i][j] * A[j][k];
            }
            // strti2
            for (int j = 0; j < 3; j++) {
                float ajj = 1.0f / A[j][j];
                A[j][j] = ajj;
                float najj = -ajj;
                for (int jj = 0; jj < j; jj++) {
                    float temp = A[jj][j];
                    for (int i = 0; i < jj; i++) A[i][j] = A[i][j] + temp * A[i][jj];
                    A[jj][j] = A[jj][j] * A[jj][jj];
                }
                for (int i = 0; i < j; i++) A[i][j] = A[i][j] * najj;
            }
            // sgetri
            for (int j = 1; j >= 0; j--) {
                float work[3];
                for (int i = j+1; i < 3; i++) { work[i] = A[i][j]; A[i][j] = 0.0f; }
                for (int k = j+1; k < 3; k++)
                    for (int i = 0; i < 3; i++)
                        A[i][j] = A[i][j] - A[i][k] * work[k];
            }
            for (int j = 2; j >= 0; j--) {
                int p = ipiv[j];
                if (p != j)
                    for (int i = 0; i < 3; i++) { float tm = A[i][j]; A[i][j] = A[i][p]; A[i][p] = tm; }
            }
            for (int k = 0; k < 9; k++) kinv[t*9 + k] = A[k/3][k%3];
        }
        return;
    }
    blk -= NB_PREP;
    // featT: [bn][c][pix] -> [bn*704+pix][c]
    {
        int bn   = blk / 11;
        int pb   = (blk % 11) * 64;
        int lane = t & 63;
        int r0   = t >> 6;
#pragma unroll
        for (int rr = 0; rr < 16; rr++) {
            int c = r0 + 4*rr;
            lds[c][lane] = feat[((size_t)bn*C_ + c)*PIX_ + pb + lane];
        }
        __syncthreads();
#pragma unroll
        for (int rr = 0; rr < 16; rr++) {
            int pr = r0 + 4*rr;
            feat_t[((size_t)bn*PIX_ + pb + pr)*C_ + lane] = lds[lane][pr];
        }
    }
}

// ---------------- enc v4: LDS weights + LDS feature window ------------------
// grid = 528 blocks (bn x 4 ytile x 11 xtile); 256 threads = 4 waves.
// Feature 6x6 window staged from feat_t (coalesced, zero-padded halo) -> all
// hot-loop accesses are LDS. fp-op sequence identical to r12 (padded zeros
// replace skipped taps: fmaf(wv,0,h)==h bit-exact).
__global__ __launch_bounds__(256) void enc_kernel(
        const float* __restrict__ feat_t,
        const float* __restrict__ w1t, const float* __restrict__ w2t,
        const float* __restrict__ bns, const float* __restrict__ bnsh,
        const float* __restrict__ b1,  const float* __restrict__ b2,
        float* __restrict__ probs) {
    __shared__ float wlds[16*9*C_];    // 36 KB: one 16-ci weight chunk
    __shared__ float flds[36][C_];     // 9 KB: 6x6 pixel window x 64 chan
    __shared__ float hl[16][C_];       // 4 KB
    int blk = blockIdx.x;              // 0..527
    int bn  = blk / 44;
    int rem = blk % 44;
    int yt  = rem / 11;
    int xt  = rem % 11;
    int t   = threadIdx.x;
    int c   = t & 63;
    int w   = __builtin_amdgcn_readfirstlane(t >> 6);   // wave id 0..3
    int y0  = yt*4;
    int x0  = xt*4;
    int y   = y0 + w;                  // this wave's output row

    // ---- stage feature window: slot s = srow*6+scol, rows y0-1..y0+4 ----
    for (int s = w; s < 36; s += 4) {
        int srow = s / 6, scol = s % 6;
        int grow = y0 - 1 + srow;
        int gcol = x0 - 1 + scol;
        float v = 0.f;
        if (grow >= 0 && grow < FH_ && gcol >= 0 && gcol < FW_)
            v = feat_t[((size_t)bn*PIX_ + grow*FW_ + gcol)*C_ + c];
        flds[s][c] = v;
    }

    float h0 = b1[c], h1 = h0, h2 = h0, h3 = h0;

    for (int cc = 0; cc < C_; cc += 16) {
        __syncthreads();               // covers flds (1st iter) + wlds reuse
        {
            const float4* s4 = (const float4*)(w1t + cc*9*C_);
            float4* d4 = (float4*)wlds;
#pragma unroll
            for (int i = 0; i < 9; i++)
                d4[t + 256*i] = s4[t + 256*i];
        }
        __syncthreads();
        for (int ci = 0; ci < 16; ci++) {
            const float* wl = wlds + ci*9*C_;
            // register-cache the 18 feature broadcasts for this ci
            float fr[3][6];
#pragma unroll
            for (int r = 0; r < 3; r++)
#pragma unroll
                for (int cl = 0; cl < 6; cl++)
                    fr[r][cl] = flds[(w + r)*6 + cl][cc + ci];
#pragma unroll
            for (int ky = 0; ky < 3; ky++) {
#pragma unroll
                for (int kx = 0; kx < 3; kx++) {
                    float wv = wl[(ky*3 + kx)*C_ + c];
                    h0 = fmaf(wv, fr[ky][kx + 0], h0);
                    h1 = fmaf(wv, fr[ky][kx + 1], h1);
                    h2 = fmaf(wv, fr[ky][kx + 2], h2);
                    h3 = fmaf(wv, fr[ky][kx + 3], h3);
                }
            }
        }
    }

    // BN + ReLU -> hl
    float sc = bns[c], sh = bnsh[c];
    {
        float v0 = fmaf(h0, sc, sh); hl[w*4 + 0][c] = v0 > 0.f ? v0 : 0.f;
        float v1 = fmaf(h1, sc, sh); hl[w*4 + 1][c] = v1 > 0.f ? v1 : 0.f;
        float v2 = fmaf(h2, sc, sh); hl[w*4 + 2][c] = v2 > 0.f ? v2 : 0.f;
        float v3 = fmaf(h3, sc, sh); hl[w*4 + 3][c] = v3 > 0.f ? v3 : 0.f;
    }
    __syncthreads();

    // conv2 (1x1): lane = depth bin d
    float l0 = b2[c], l1 = l0, l2 = l0, l3 = l0;
    for (int c2 = 0; c2 < C_; c2++) {
        float wv = w2t[c2*D_ + c];
        l0 = fmaf(wv, hl[w*4 + 0][c2], l0);
        l1 = fmaf(wv, hl[w*4 + 1][c2], l1);
        l2 = fmaf(wv, hl[w*4 + 2][c2], l2);
        l3 = fmaf(wv, hl[w*4 + 3][c2], l3);
    }

    // softmax over the 64 lanes
    float lv[4] = {l0, l1, l2, l3};
#pragma unroll
    for (int p = 0; p < 4; p++) {
        float l = lv[p];
        float m = l;
        for (int off = 32; off; off >>= 1) m = fmaxf(m, __shfl_xor(m, off));
        float e = expf(l - m);
        float s = e;
        for (int off = 32; off; off >>= 1) s += __shfl_xor(s, off);
        probs[((size_t)bn*PIX_ + y*FW_ + x0 + p)*D_ + c] = e / s;
    }
}

// ---------------- geometry: cell for point i (f32 chain, validated r4) ------
__device__ __forceinline__ int compute_cell(int i, const float* __restrict__ kinv,
                                            const float* __restrict__ ext) {
#pragma clang fp contract(off)
    int x  = i % FW_;
    int y  = (i / FW_) % FH_;
    int d  = (i / PIX_) % D_;
    int bn = i / PPBN;

    const float* kv = kinv + bn*9;
    const float* e  = ext  + bn*16;

    float u  = (x == FW_-1) ? 703.0f : (float)((double)x * (703.0/43.0));
    float vv = (float)((double)y * 17.0);
    float dd = (d == D_-1) ? 60.0f  : (float)(1.0 + (double)d * (59.0/63.0));

    float px = u * dd;
    float py = vv * dd;
    float pz = dd;

    float cx = (kv[0]*px + kv[1]*py) + kv[2]*pz;
    float cy = (kv[3]*px + kv[4]*py) + kv[5]*pz;
    float cz = (kv[6]*px + kv[7]*py) + kv[8]*pz;

    float ex = (e[0]*cx + e[1]*cy) + e[2]*cz;
    float ey = (e[4]*cx + e[5]*cy) + e[6]*cz;
    ex = ex + e[3];
    ey = ey + e[7];

    float gx = (ex + 50.0f) / 0.5f;
    float gy = (ey + 50.0f) / 0.5f;
    int ix = (int)floorf(gx);
    int iy = (int)floorf(gy);
    return (ix >= 0 && ix < BEVW && iy >= 0 && iy < BEVH) ? (iy*BEVW + ix) : -1;
}

// ---- wave run-aggregation helpers ----
__device__ __forceinline__ void run_info(int fc, int lane,
                                         bool& isLeader, int& runLen, int& lead) {
    int prev = __shfl_up(fc, 1);
    isLeader = (lane == 0) || (fc != prev);
    unsigned long long mask = __ballot(isLeader);
    unsigned long long hi = (lane == 63) ? 0ull : (mask >> (lane + 1));
    int next = hi ? (lane + 1 + __builtin_ctzll(hi)) : 64;
    runLen = next - lane;
    unsigned long long lo = mask & (~0ull >> (63 - lane));
    lead = 63 - __builtin_clzll(lo);
}

// ---------------- geom + histogram (wave-aggregated) ----------------
__global__ __launch_bounds__(256) void geomhist_kernel(
        const float* __restrict__ ext, const float* __restrict__ kinv,
        int* __restrict__ counts) {
    int i = blockIdx.x * 256 + threadIdx.x;
    int lane = threadIdx.x & 63;
    int fc = -1;
    if (i < NPTS) {
        int cell = compute_cell(i, kinv, ext);
        if (cell >= 0) fc = (i / (PPBN * N_)) * NCELL + cell;
    }
    bool isLeader; int runLen, lead;
    run_info(fc, lane, isLeader, runLen, lead);
    if (isLeader && fc >= 0) atomicAdd(&counts[fc], runLen);
}

// ---------------- scanA: block-local scan ----------------
__global__ __launch_bounds__(256) void scanA_kernel(
        int* __restrict__ startp, int* __restrict__ cursor, int* __restrict__ bsum) {
    __shared__ int sdata[256];
    int t = threadIdx.x;
    int i = blockIdx.x * 256 + t;
    int v = (i < NBCELL) ? startp[1 + i] : 0;
    sdata[t] = v;
    __syncthreads();
#pragma unroll
    for (int off = 1; off < 256; off <<= 1) {
        int add = (t >= off) ? sdata[t - off] : 0;
        __syncthreads();
        sdata[t] += add;
        __syncthreads();
    }
    if (i < NBCELL) {
        startp[1 + i] = sdata[t];
        cursor[i]     = sdata[t] - v;
    }
    if (t == 255) bsum[blockIdx.x] = sdata[255];
}

// ---------------- scanC': re-scan bsum in LDS + apply offsets ---------------
__global__ __launch_bounds__(512) void scanC_kernel(
        int* __restrict__ startp, int* __restrict__ cursor,
        const int* __restrict__ bsum) {
    __shared__ int sdata[512];
    int t = threadIdx.x;
    int v = (t < NSCANB) ? bsum[t] : 0;
    sdata[t] = v;
    __syncthreads();
#pragma unroll
    for (int off = 1; off < 512; off <<= 1) {
        int add = (t >= off) ? sdata[t - off] : 0;
        __syncthreads();
        sdata[t] += add;
        __syncthreads();
    }
    int i = blockIdx.x * 512 + t;
    if (i >= NBCELL) return;
    int j = i >> 8;                       // which scanA block
    int off = (j == 0) ? 0 : sdata[j - 1];
    startp[1 + i] += off;
    cursor[i]     += off;
}

// ---------------- geom + scatter packed records (wave-aggregated) -----------
// record: .x = prob bits, .y = pixg | (fc << 14)
__global__ __launch_bounds__(256) void geomscatter_kernel(
        const float* __restrict__ ext, const float* __restrict__ kinv,
        const float* __restrict__ probs,
        int* __restrict__ cursor, int2* __restrict__ plist2) {
    int i = blockIdx.x * 256 + threadIdx.x;
    int lane = threadIdx.x & 63;
    int fc = -1, pixg = 0;
    float pr = 0.f;
    if (i < NPTS) {
        int cell = compute_cell(i, kinv, ext);
        if (cell >= 0) {
            int pix = i % PIX_;
            int d   = (i / PIX_) % D_;
            int bn  = i / PPBN;
            fc   = (bn / N_) * NCELL + cell;
            pixg = bn*PIX_ + pix;
            pr   = probs[(size_t)pixg*D_ + d];
        }
    }
    bool isLeader; int runLen, lead;
    run_info(fc, lane, isLeader, runLen, lead);
    int base = 0;
    if (isLeader && fc >= 0) base = atomicAdd(&cursor[fc], runLen);
    base = __shfl(base, lead);
    if (fc >= 0)
        plist2[base + (lane - lead)] = make_int2(__float_as_int(pr),
                                                 pixg | (fc << 14));
}

// ---------------- gather3: point-balanced, ownership-based ------------------
__global__ __launch_bounds__(256) void gather3_kernel(
        const float* __restrict__ feat_t, const int* __restrict__ startp,
        const int2* __restrict__ plist2, float* __restrict__ out) {
    int gid  = blockIdx.x * 256 + threadIdx.x;
    int W    = gid >> 6;
    int lane = gid & 63;
    int total = startp[NBCELL];
    int p0 = W * PPW;
    if (p0 >= total) return;
    int pe = min(p0 + PPW, total);
    int p  = p0;

    // head: cell continuing from a previous wave's range
    {
        int2 r = plist2[p0];
        int fc = ((unsigned)r.y) >> 14;
        int cs = startp[fc], ce = startp[fc + 1];
        if (cs < p0) {
            if (ce - cs > 2*PPW) {        // big: process our slice
                int b2 = min(pe, ce);
                float acc = 0.f;
                for (int q = p0; q < b2; q++) {
                    int2 rr = plist2[q];
                    acc = fmaf(__int_as_float(rr.x),
                               feat_t[(size_t)(rr.y & 0x3FFF)*C_ + lane], acc);
                }
                int bb   = fc >= NCELL;
                int cell = fc - bb*NCELL;
                atomicAdd(out + ((size_t)(bb*C_ + lane))*NCELL + cell, acc);
            }
            p = ce;                        // small: skip (owned upstream)
        }
    }
    // cells starting in [p, pe)
    while (p < pe) {
        int2 r = plist2[p];
        int fc = ((unsigned)r.y) >> 14;
        int ce = startp[fc + 1];
        int len = ce - p;                  // p == cell start here
        bool big = (len > 2*PPW);
        int b2 = big ? min(ce, pe) : ce;   // small may extend past pe (owned)
        float acc = 0.f;
        for (int q = p; q < b2; q++) {
            int2 rr = plist2[q];
            acc = fmaf(__int_as_float(rr.x),
                       feat_t[(size_t)(rr.y & 0x3FFF)*C_ + lane], acc);
        }
        int bb   = fc >= NCELL;
        int cell = fc - bb*NCELL;
        float* addr = out + ((size_t)(bb*C_ + lane))*NCELL + cell;
        if (big) atomicAdd(addr, acc);
        else     *addr = acc;
        p = ce;
    }
}

extern "C" void kernel_launch(void* const* d_in, const int* in_sizes, int n_in,
                              void* d_out, int out_size, void* d_ws, size_t ws_size,
                              hipStream_t stream) {
    const float* feat  = (const float*)d_in[0];
    const float* intr  = (const float*)d_in[1];
    const float* ext   = (const float*)d_in[2];
    const float* w1    = (const float*)d_in[3];
    const float* b1    = (const float*)d_in[4];
    const float* gamma = (const float*)d_in[5];
    const float* beta  = (const float*)d_in[6];
    const float* rmean = (const float*)d_in[7];
    const float* rvar  = (const float*)d_in[8];
    const float* w2    = (const float*)d_in[9];
    const float* b2    = (const float*)d_in[10];
    float* out = (float*)d_out;
    (void)in_sizes; (void)n_in; (void)out_size; (void)ws_size;

    // workspace layout (plist2 first for 8B alignment); total ~9.5 MB
    int2*  plist2 = (int2*)d_ws;                    // NPTS int2 = 4.33 MB
    float* w1t    = (float*)(plist2 + NPTS);        // 36864
    float* w2t    = w1t + C_*C_*9;                  // 4096
    float* bns    = w2t + D_*C_;                    // 64
    float* bnsh   = bns + C_;                       // 64
    float* kinv   = bnsh + C_;                      // 108
    float* probs  = kinv + BN_*9;                   // 540672
    float* feat_t = probs + NPTS;                   // 540672
    int*   startp = (int*)(feat_t + NPTS);          // 80001
    int*   cursor = startp + (NBCELL + 1);          // 80000
    int*   bsum   = cursor + NBCELL;                // 313

    // ---- 7-launch pipeline ----
    setup_kernel<<<NB_SETUP, 256, 0, stream>>>(feat, w1, w2, gamma, beta,
                                               rmean, rvar, intr, out, startp,
                                               w1t, w2t, bns, bnsh, kinv, feat_t);
    enc_kernel<<<528, 256, 0, stream>>>(feat_t, w1t, w2t, bns, bnsh, b1, b2, probs);
    geomhist_kernel<<<NPTS/256, 256, 0, stream>>>(ext, kinv, startp + 1);
    scanA_kernel<<<NSCANB, 256, 0, stream>>>(startp, cursor, bsum);
    scanC_kernel<<<(NBCELL + 511)/512, 512, 0, stream>>>(startp, cursor, bsum);
    geomscatter_kernel<<<NPTS/256, 256, 0, stream>>>(ext, kinv, probs, cursor, plist2);
    gather3_kernel<<<GBLK, 256, 0, stream>>>(feat_t, startp, plist2, out);
}

// Round 14
// 210.587 us; speedup vs baseline: 12.1485x; 1.0619x over previous
//
#include <hip/hip_runtime.h>
#include <math.h>

#define B_   2
#define N_   6
#define C_   64
#define D_   64
#define FH_  16
#define FW_  44
#define BN_  (B_*N_)              // 12
#define PIX_ (FH_*FW_)            // 704
#define NPIX (BN_*PIX_)           // 8448
#define NPTS (BN_*D_*PIX_)        // 540672
#define PPBN (D_*PIX_)            // 45056 points per (b,n) image
#define BEVH 200
#define BEVW 200
#define NCELL (BEVH*BEVW)         // 40000
#define NBCELL (B_*NCELL)         // 80000
#define NSCANB ((NBCELL + 255)/256)  // 313 scan blocks
#define PPW  64                   // points per wave in gather
#define GBLK (NPTS/(PPW*4))       // 2112 gather blocks (4 waves each)
// record pack: pixg (14 bits, max 8447) | fc << 14 (17 bits, max 79999) -> <2^31

// setup mega-kernel block ranges
#define NB_ZOUT 5000              // out zero: 5.12M f32 = 1.28M float4
#define NB_ZSP  313               // startp zero (80001 ints)
#define NB_TW   160               // weight transposes (40960 elems)
#define NB_PREP 1                 // BN affine + Kinv
#define NB_FT   132               // feat transpose
#define NB_SETUP (NB_ZOUT + NB_ZSP + NB_TW + NB_PREP + NB_FT)   // 5606

// ---------------- setup: zero out + zero startp + transW + prep + featT -----
__global__ __launch_bounds__(256) void setup_kernel(
        const float* __restrict__ feat, const float* __restrict__ w1,
        const float* __restrict__ w2,
        const float* __restrict__ gamma, const float* __restrict__ beta,
        const float* __restrict__ rmean, const float* __restrict__ rvar,
        const float* __restrict__ intr,
        float* __restrict__ out, int* __restrict__ startp,
        float* __restrict__ w1t, float* __restrict__ w2t,
        float* __restrict__ bns, float* __restrict__ bnsh,
        float* __restrict__ kinv, float* __restrict__ feat_t) {
#pragma clang fp contract(off)
    __shared__ float lds[64][65];
    int blk = blockIdx.x;
    int t   = threadIdx.x;

    if (blk < NB_ZOUT) {
        ((float4*)out)[blk*256 + t] = float4{0.f, 0.f, 0.f, 0.f};
        return;
    }
    blk -= NB_ZOUT;
    if (blk < NB_ZSP) {
        int i = blk*256 + t;
        if (i < NBCELL + 1) startp[i] = 0;
        return;
    }
    blk -= NB_ZSP;
    if (blk < NB_TW) {
        int idx = blk*256 + t;
        if (idx < C_*C_*9) {
            int cout = idx / (C_*9);
            int r    = idx % (C_*9);
            w1t[r*C_ + cout] = w1[idx];
        } else if (idx < C_*C_*9 + D_*C_) {
            int j = idx - C_*C_*9;
            int d = j / C_, c = j % C_;
            w2t[c*D_ + d] = w2[j];
        }
        return;
    }
    blk -= NB_TW;
    if (blk < NB_PREP) {
        if (t < C_) {
            float s = gamma[t] / sqrtf(rvar[t] + 1e-5f);
            bns[t]  = s;
            bnsh[t] = beta[t] - rmean[t] * s;
        }
        if (t < BN_) {
            const float* K = intr + t*9;
            float A[3][3];
            for (int r = 0; r < 3; r++)
                for (int cc = 0; cc < 3; cc++) A[r][cc] = K[r*3 + cc];
            int ipiv[3];
            // sgetf2
            for (int j = 0; j < 3; j++) {
                int p = j; float mx = fabsf(A[j][j]);
                for (int i = j+1; i < 3; i++) {
                    float v = fabsf(A[i][j]);
                    if (v > mx) { mx = v; p = i; }
                }
                ipiv[j] = p;
                if (p != j)
                    for (int k = 0; k < 3; k++) { float tm = A[j][k]; A[j][k] = A[p][k]; A[p][k] = tm; }
                float rpiv = 1.0f / A[j][j];
                for (int i = j+1; i < 3; i++) A[i][j] = A[i][j] * rpiv;
                for (int k = j+1; k < 3; k++)
                    for (int i = j+1; i < 3; i++)
                        A[i][k] = A[i][k] - A[i][j] * A[j][k];
            }
            // strti2
            for (int j = 0; j < 3; j++) {
                float ajj = 1.0f / A[j][j];
                A[j][j] = ajj;
                float najj = -ajj;
                for (int jj = 0; jj < j; jj++) {
                    float temp = A[jj][j];
                    for (int i = 0; i < jj; i++) A[i][j] = A[i][j] + temp * A[i][jj];
                    A[jj][j] = A[jj][j] * A[jj][jj];
                }
                for (int i = 0; i < j; i++) A[i][j] = A[i][j] * najj;
            }
            // sgetri
            for (int j = 1; j >= 0; j--) {
                float work[3];
                for (int i = j+1; i < 3; i++) { work[i] = A[i][j]; A[i][j] = 0.0f; }
                for (int k = j+1; k < 3; k++)
                    for (int i = 0; i < 3; i++)
                        A[i][j] = A[i][j] - A[i][k] * work[k];
            }
            for (int j = 2; j >= 0; j--) {
                int p = ipiv[j];
                if (p != j)
                    for (int i = 0; i < 3; i++) { float tm = A[i][j]; A[i][j] = A[i][p]; A[i][p] = tm; }
            }
            for (int k = 0; k < 9; k++) kinv[t*9 + k] = A[k/3][k%3];
        }
        return;
    }
    blk -= NB_PREP;
    // featT: [bn][c][pix] -> [bn*704+pix][c]
    {
        int bn   = blk / 11;
        int pb   = (blk % 11) * 64;
        int lane = t & 63;
        int r0   = t >> 6;
#pragma unroll
        for (int rr = 0; rr < 16; rr++) {
            int c = r0 + 4*rr;
            lds[c][lane] = feat[((size_t)bn*C_ + c)*PIX_ + pb + lane];
        }
        __syncthreads();
#pragma unroll
        for (int rr = 0; rr < 16; rr++) {
            int pr = r0 + 4*rr;
            feat_t[((size_t)bn*PIX_ + pb + pr)*C_ + lane] = lds[lane][pr];
        }
    }
}

// ---------------- enc v4: LDS weights + LDS feature window ------------------
__global__ __launch_bounds__(256) void enc_kernel(
        const float* __restrict__ feat_t,
        const float* __restrict__ w1t, const float* __restrict__ w2t,
        const float* __restrict__ bns, const float* __restrict__ bnsh,
        const float* __restrict__ b1,  const float* __restrict__ b2,
        float* __restrict__ probs) {
    __shared__ float wlds[16*9*C_];    // 36 KB: one 16-ci weight chunk
    __shared__ float flds[36][C_];     // 9 KB: 6x6 pixel window x 64 chan
    __shared__ float hl[16][C_];       // 4 KB
    int blk = blockIdx.x;              // 0..527
    int bn  = blk / 44;
    int rem = blk % 44;
    int yt  = rem / 11;
    int xt  = rem % 11;
    int t   = threadIdx.x;
    int c   = t & 63;
    int w   = __builtin_amdgcn_readfirstlane(t >> 6);   // wave id 0..3
    int y0  = yt*4;
    int x0  = xt*4;
    int y   = y0 + w;

    // stage feature window (zero-padded halo), coalesced from feat_t
    for (int s = w; s < 36; s += 4) {
        int srow = s / 6, scol = s % 6;
        int grow = y0 - 1 + srow;
        int gcol = x0 - 1 + scol;
        float v = 0.f;
        if (grow >= 0 && grow < FH_ && gcol >= 0 && gcol < FW_)
            v = feat_t[((size_t)bn*PIX_ + grow*FW_ + gcol)*C_ + c];
        flds[s][c] = v;
    }

    float h0 = b1[c], h1 = h0, h2 = h0, h3 = h0;

    for (int cc = 0; cc < C_; cc += 16) {
        __syncthreads();
        {
            const float4* s4 = (const float4*)(w1t + cc*9*C_);
            float4* d4 = (float4*)wlds;
#pragma unroll
            for (int i = 0; i < 9; i++)
                d4[t + 256*i] = s4[t + 256*i];
        }
        __syncthreads();
        for (int ci = 0; ci < 16; ci++) {
            const float* wl = wlds + ci*9*C_;
            float fr[3][6];
#pragma unroll
            for (int r = 0; r < 3; r++)
#pragma unroll
                for (int cl = 0; cl < 6; cl++)
                    fr[r][cl] = flds[(w + r)*6 + cl][cc + ci];
#pragma unroll
            for (int ky = 0; ky < 3; ky++) {
#pragma unroll
                for (int kx = 0; kx < 3; kx++) {
                    float wv = wl[(ky*3 + kx)*C_ + c];
                    h0 = fmaf(wv, fr[ky][kx + 0], h0);
                    h1 = fmaf(wv, fr[ky][kx + 1], h1);
                    h2 = fmaf(wv, fr[ky][kx + 2], h2);
                    h3 = fmaf(wv, fr[ky][kx + 3], h3);
                }
            }
        }
    }

    float sc = bns[c], sh = bnsh[c];
    {
        float v0 = fmaf(h0, sc, sh); hl[w*4 + 0][c] = v0 > 0.f ? v0 : 0.f;
        float v1 = fmaf(h1, sc, sh); hl[w*4 + 1][c] = v1 > 0.f ? v1 : 0.f;
        float v2 = fmaf(h2, sc, sh); hl[w*4 + 2][c] = v2 > 0.f ? v2 : 0.f;
        float v3 = fmaf(h3, sc, sh); hl[w*4 + 3][c] = v3 > 0.f ? v3 : 0.f;
    }
    __syncthreads();

    float l0 = b2[c], l1 = l0, l2 = l0, l3 = l0;
    for (int c2 = 0; c2 < C_; c2++) {
        float wv = w2t[c2*D_ + c];
        l0 = fmaf(wv, hl[w*4 + 0][c2], l0);
        l1 = fmaf(wv, hl[w*4 + 1][c2], l1);
        l2 = fmaf(wv, hl[w*4 + 2][c2], l2);
        l3 = fmaf(wv, hl[w*4 + 3][c2], l3);
    }

    float lv[4] = {l0, l1, l2, l3};
#pragma unroll
    for (int p = 0; p < 4; p++) {
        float l = lv[p];
        float m = l;
        for (int off = 32; off; off >>= 1) m = fmaxf(m, __shfl_xor(m, off));
        float e = expf(l - m);
        float s = e;
        for (int off = 32; off; off >>= 1) s += __shfl_xor(s, off);
        probs[((size_t)bn*PIX_ + y*FW_ + x0 + p)*D_ + c] = e / s;
    }
}

// ---------------- geometry: cell for point i (f32 chain, validated r4) ------
__device__ __forceinline__ int compute_cell(int i, const float* __restrict__ kinv,
                                            const float* __restrict__ ext) {
#pragma clang fp contract(off)
    int x  = i % FW_;
    int y  = (i / FW_) % FH_;
    int d  = (i / PIX_) % D_;
    int bn = i / PPBN;

    const float* kv = kinv + bn*9;
    const float* e  = ext  + bn*16;

    float u  = (x == FW_-1) ? 703.0f : (float)((double)x * (703.0/43.0));
    float vv = (float)((double)y * 17.0);
    float dd = (d == D_-1) ? 60.0f  : (float)(1.0 + (double)d * (59.0/63.0));

    float px = u * dd;
    float py = vv * dd;
    float pz = dd;

    float cx = (kv[0]*px + kv[1]*py) + kv[2]*pz;
    float cy = (kv[3]*px + kv[4]*py) + kv[5]*pz;
    float cz = (kv[6]*px + kv[7]*py) + kv[8]*pz;

    float ex = (e[0]*cx + e[1]*cy) + e[2]*cz;
    float ey = (e[4]*cx + e[5]*cy) + e[6]*cz;
    ex = ex + e[3];
    ey = ey + e[7];

    float gx = (ex + 50.0f) / 0.5f;
    float gy = (ey + 50.0f) / 0.5f;
    int ix = (int)floorf(gx);
    int iy = (int)floorf(gy);
    return (ix >= 0 && ix < BEVW && iy >= 0 && iy < BEVH) ? (iy*BEVW + ix) : -1;
}

// ---- wave run-aggregation helpers ----
__device__ __forceinline__ void run_info(int fc, int lane,
                                         bool& isLeader, int& runLen, int& lead) {
    int prev = __shfl_up(fc, 1);
    isLeader = (lane == 0) || (fc != prev);
    unsigned long long mask = __ballot(isLeader);
    unsigned long long hi = (lane == 63) ? 0ull : (mask >> (lane + 1));
    int next = hi ? (lane + 1 + __builtin_ctzll(hi)) : 64;
    runLen = next - lane;
    unsigned long long lo = mask & (~0ull >> (63 - lane));
    lead = 63 - __builtin_clzll(lo);
}

// ---------------- geom + histogram (wave-aggregated) ----------------
__global__ __launch_bounds__(256) void geomhist_kernel(
        const float* __restrict__ ext, const float* __restrict__ kinv,
        int* __restrict__ counts) {
    int i = blockIdx.x * 256 + threadIdx.x;
    int lane = threadIdx.x & 63;
    int fc = -1;
    if (i < NPTS) {
        int cell = compute_cell(i, kinv, ext);
        if (cell >= 0) fc = (i / (PPBN * N_)) * NCELL + cell;
    }
    bool isLeader; int runLen, lead;
    run_info(fc, lane, isLeader, runLen, lead);
    if (isLeader && fc >= 0) atomicAdd(&counts[fc], runLen);
}

// ---------------- scanA: block-local scan ----------------
__global__ __launch_bounds__(256) void scanA_kernel(
        int* __restrict__ startp, int* __restrict__ cursor, int* __restrict__ bsum) {
    __shared__ int sdata[256];
    int t = threadIdx.x;
    int i = blockIdx.x * 256 + t;
    int v = (i < NBCELL) ? startp[1 + i] : 0;
    sdata[t] = v;
    __syncthreads();
#pragma unroll
    for (int off = 1; off < 256; off <<= 1) {
        int add = (t >= off) ? sdata[t - off] : 0;
        __syncthreads();
        sdata[t] += add;
        __syncthreads();
    }
    if (i < NBCELL) {
        startp[1 + i] = sdata[t];
        cursor[i]     = sdata[t] - v;
    }
    if (t == 255) bsum[blockIdx.x] = sdata[255];
}

// ---------------- scanC': re-scan bsum in LDS + apply offsets ---------------
__global__ __launch_bounds__(512) void scanC_kernel(
        int* __restrict__ startp, int* __restrict__ cursor,
        const int* __restrict__ bsum) {
    __shared__ int sdata[512];
    int t = threadIdx.x;
    int v = (t < NSCANB) ? bsum[t] : 0;
    sdata[t] = v;
    __syncthreads();
#pragma unroll
    for (int off = 1; off < 512; off <<= 1) {
        int add = (t >= off) ? sdata[t - off] : 0;
        __syncthreads();
        sdata[t] += add;
        __syncthreads();
    }
    int i = blockIdx.x * 512 + t;
    if (i >= NBCELL) return;
    int j = i >> 8;                       // which scanA block
    int off = (j == 0) ? 0 : sdata[j - 1];
    startp[1 + i] += off;
    cursor[i]     += off;
}

// ---------------- geom + scatter packed records (wave-aggregated) -----------
// record: .x = prob bits, .y = pixg | (fc << 14)
__global__ __launch_bounds__(256) void geomscatter_kernel(
        const float* __restrict__ ext, const float* __restrict__ kinv,
        const float* __restrict__ probs,
        int* __restrict__ cursor, int2* __restrict__ plist2) {
    int i = blockIdx.x * 256 + threadIdx.x;
    int lane = threadIdx.x & 63;
    int fc = -1, pixg = 0;
    float pr = 0.f;
    if (i < NPTS) {
        int cell = compute_cell(i, kinv, ext);
        if (cell >= 0) {
            int pix = i % PIX_;
            int d   = (i / PIX_) % D_;
            int bn  = i / PPBN;
            fc   = (bn / N_) * NCELL + cell;
            pixg = bn*PIX_ + pix;
            pr   = probs[(size_t)pixg*D_ + d];
        }
    }
    bool isLeader; int runLen, lead;
    run_info(fc, lane, isLeader, runLen, lead);
    int base = 0;
    if (isLeader && fc >= 0) base = atomicAdd(&cursor[fc], runLen);
    base = __shfl(base, lead);
    if (fc >= 0)
        plist2[base + (lane - lead)] = make_int2(__float_as_int(pr),
                                                 pixg | (fc << 14));
}

// ---- 4-way ILP cell accumulation: 4 independent FMA chains, loads batched --
__device__ __forceinline__ float cell_accum(
        const int2* __restrict__ plist2, const float* __restrict__ feat_t,
        int q0, int q1, int lane) {
    float a0 = 0.f, a1 = 0.f, a2 = 0.f, a3 = 0.f;
    int q = q0;
    for (; q + 4 <= q1; q += 4) {
        int2 r0 = plist2[q];
        int2 r1 = plist2[q + 1];
        int2 r2 = plist2[q + 2];
        int2 r3 = plist2[q + 3];
        float f0 = feat_t[(size_t)(r0.y & 0x3FFF)*C_ + lane];
        float f1 = feat_t[(size_t)(r1.y & 0x3FFF)*C_ + lane];
        float f2 = feat_t[(size_t)(r2.y & 0x3FFF)*C_ + lane];
        float f3 = feat_t[(size_t)(r3.y & 0x3FFF)*C_ + lane];
        a0 = fmaf(__int_as_float(r0.x), f0, a0);
        a1 = fmaf(__int_as_float(r1.x), f1, a1);
        a2 = fmaf(__int_as_float(r2.x), f2, a2);
        a3 = fmaf(__int_as_float(r3.x), f3, a3);
    }
    for (; q < q1; q++) {
        int2 r = plist2[q];
        a0 = fmaf(__int_as_float(r.x),
                  feat_t[(size_t)(r.y & 0x3FFF)*C_ + lane], a0);
    }
    return (a0 + a1) + (a2 + a3);
}

// ---------------- gather4: point-balanced + 4-way ILP ------------------------
// wave W covers plist[W*PPW, (W+1)*PPW) snapped to cell boundaries.
// small cell (len<=2*PPW): owned by the wave containing its START -> store.
// big cell: each overlapping wave adds its slice via atomicAdd.
__global__ __launch_bounds__(256) void gather4_kernel(
        const float* __restrict__ feat_t, const int* __restrict__ startp,
        const int2* __restrict__ plist2, float* __restrict__ out) {
    int gid  = blockIdx.x * 256 + threadIdx.x;
    int W    = gid >> 6;
    int lane = gid & 63;
    int total = startp[NBCELL];
    int p0 = W * PPW;
    if (p0 >= total) return;
    int pe = min(p0 + PPW, total);
    int p  = p0;

    // head: cell continuing from a previous wave's range
    {
        int2 r = plist2[p0];
        int fc = ((unsigned)r.y) >> 14;
        int cs = startp[fc], ce = startp[fc + 1];
        if (cs < p0) {
            if (ce - cs > 2*PPW) {        // big: process our slice
                float acc = cell_accum(plist2, feat_t, p0, min(pe, ce), lane);
                int bb   = fc >= NCELL;
                int cell = fc - bb*NCELL;
                atomicAdd(out + ((size_t)(bb*C_ + lane))*NCELL + cell, acc);
            }
            p = ce;                        // small: skip (owned upstream)
        }
    }
    // cells starting in [p, pe)
    while (p < pe) {
        int2 r = plist2[p];
        int fc = ((unsigned)r.y) >> 14;
        int ce = startp[fc + 1];
        bool big = (ce - p > 2*PPW);
        int b2 = big ? min(ce, pe) : ce;   // small may extend past pe (owned)
        float acc = cell_accum(plist2, feat_t, p, b2, lane);
        int bb   = fc >= NCELL;
        int cell = fc - bb*NCELL;
        float* addr = out + ((size_t)(bb*C_ + lane))*NCELL + cell;
        if (big) atomicAdd(addr, acc);
        else     *addr = acc;
        p = ce;
    }
}

extern "C" void kernel_launch(void* const* d_in, const int* in_sizes, int n_in,
                              void* d_out, int out_size, void* d_ws, size_t ws_size,
                              hipStream_t stream) {
    const float* feat  = (const float*)d_in[0];
    const float* intr  = (const float*)d_in[1];
    const float* ext   = (const float*)d_in[2];
    const float* w1    = (const float*)d_in[3];
    const float* b1    = (const float*)d_in[4];
    const float* gamma = (const float*)d_in[5];
    const float* beta  = (const float*)d_in[6];
    const float* rmean = (const float*)d_in[7];
    const float* rvar  = (const float*)d_in[8];
    const float* w2    = (const float*)d_in[9];
    const float* b2    = (const float*)d_in[10];
    float* out = (float*)d_out;
    (void)in_sizes; (void)n_in; (void)out_size; (void)ws_size;

    // workspace layout (plist2 first for 8B alignment); total ~9.5 MB
    int2*  plist2 = (int2*)d_ws;                    // NPTS int2 = 4.33 MB
    float* w1t    = (float*)(plist2 + NPTS);        // 36864
    float* w2t    = w1t + C_*C_*9;                  // 4096
    float* bns    = w2t + D_*C_;                    // 64
    float* bnsh   = bns + C_;                       // 64
    float* kinv   = bnsh + C_;                      // 108
    float* probs  = kinv + BN_*9;                   // 540672
    float* feat_t = probs + NPTS;                   // 540672
    int*   startp = (int*)(feat_t + NPTS);          // 80001
    int*   cursor = startp + (NBCELL + 1);          // 80000
    int*   bsum   = cursor + NBCELL;                // 313

    // ---- 7-launch pipeline ----
    setup_kernel<<<NB_SETUP, 256, 0, stream>>>(feat, w1, w2, gamma, beta,
                                               rmean, rvar, intr, out, startp,
                                               w1t, w2t, bns, bnsh, kinv, feat_t);
    enc_kernel<<<528, 256, 0, stream>>>(feat_t, w1t, w2t, bns, bnsh, b1, b2, probs);
    geomhist_kernel<<<NPTS/256, 256, 0, stream>>>(ext, kinv, startp + 1);
    scanA_kernel<<<NSCANB, 256, 0, stream>>>(startp, cursor, bsum);
    scanC_kernel<<<(NBCELL + 511)/512, 512, 0, stream>>>(startp, cursor, bsum);
    geomscatter_kernel<<<NPTS/256, 256, 0, stream>>>(ext, kinv, probs, cursor, plist2);
    gather4_kernel<<<GBLK, 256, 0, stream>>>(feat_t, startp, plist2, out);
}